// Round 2
// baseline (721.101 us; speedup 1.0000x reference)
//
#include <hip/hip_runtime.h>
#include <hip/hip_bf16.h>
#include <math.h>

// Problem constants (fixed by setup_inputs)
#define B_    16
#define C_    256
#define P_    16384          // 128*128
#define K_    101            // num_class + 1
#define S_    17             // B + 1 slots per class
#define V_    1717           // K_ * S_
#define GN_   1792           // V_ padded to 14*128
#define KPAD_ 102            // class stride in LDS (dummy slot for OOB labels)
#define TEMP_ 0.07f
#define INV_SQRT_T 3.7796447300922720f   // 1/sqrt(0.07)

__device__ __forceinline__ void atomAddGlb(float* p, float v) {
  __hip_atomic_fetch_add(p, v, __ATOMIC_RELAXED, __HIP_MEMORY_SCOPE_AGENT);
}

// ---------------------------------------------------------------------------
// K1: per-(batch,class) masked sums + counts.
// 512 linear blocks encode (tile,b,zh) such that the 16 tile-blocks of a
// given (b,zh) share id%8 -> same XCD -> flush atomics stay in one L2.
// LDS accumulate via atomicAdd on the __shared__ array itself (ds_add_f32).
// ---------------------------------------------------------------------------
__global__ __launch_bounds__(1024) void k_segsum(
    const int* __restrict__ labels, const float* __restrict__ feats,
    float* __restrict__ sums, unsigned* __restrict__ counts) {
  __shared__ float s_acc[128 * KPAD_];
  __shared__ int s_lab[1024];
  __shared__ unsigned s_cnt[KPAD_];
  const int id = blockIdx.x;
  const int q = (id & 7) + ((id >> 7) << 3);  // q = b*2 + zh, constant id%8 per q
  const int tile = (id >> 3) & 15;
  const int b = q >> 1, zh = q & 1;
  const int tid = threadIdx.x;
  for (int i = tid; i < 128 * KPAD_; i += 1024) s_acc[i] = 0.f;
  if (zh == 0 && tid < KPAD_) s_cnt[tid] = 0u;
  const int p0 = tile * 1024;
  int lab = labels[b * P_ + p0 + tid];
  if ((unsigned)lab > 100u) lab = 101;  // route OOB labels to dummy slot
  s_lab[tid] = lab;
  __syncthreads();
  if (zh == 0) atomicAdd(&s_cnt[lab], 1u);
  const int wv = tid >> 6, ln = tid & 63;
  const float* fb = feats + ((size_t)b * C_ + (size_t)zh * 128) * P_ + p0;
  for (int g = 0; g < 4; ++g) {
    const int pb = g * 256 + ln * 4;
    const int4 lv = *(const int4*)&s_lab[pb];
#pragma unroll
    for (int j = 0; j < 8; ++j) {
      const int cl = wv * 8 + j;
      const float4 f = *(const float4*)&fb[(size_t)cl * P_ + pb];
      const int sA = cl * KPAD_;
      atomicAdd(&s_acc[sA + lv.x], f.x);
      atomicAdd(&s_acc[sA + lv.y], f.y);
      atomicAdd(&s_acc[sA + lv.z], f.z);
      atomicAdd(&s_acc[sA + lv.w], f.w);
    }
  }
  __syncthreads();
  for (int i = tid; i < 128 * KPAD_; i += 1024) {
    const int cl = i / KPAD_, kk = i - cl * KPAD_;
    const float v = s_acc[i];
    if (kk < K_ && v != 0.f)
      atomAddGlb(&sums[((size_t)b * K_ + kk) * C_ + zh * 128 + cl], v);
  }
  if (zh == 0) {
    for (int i = tid; i < K_; i += 1024) {
      const unsigned cv = s_cnt[i];
      if (cv) atomicAdd(&counts[b * K_ + i], cv);
    }
  }
}

// ---------------------------------------------------------------------------
// K2: build normalized prototype slots (pre-scaled by 1/sqrt(T)), valid mask,
// per-class cnt, per-column weight, cnt_exist. grid K_ blocks, 256 threads.
// ---------------------------------------------------------------------------
__global__ __launch_bounds__(256) void k_protos(
    const float* __restrict__ sums, const unsigned* __restrict__ counts,
    const float* __restrict__ prototypes, float* __restrict__ Pm,
    int* __restrict__ valid, float* __restrict__ wcol,
    float* __restrict__ cntk, float* __restrict__ scal) {
  const int k = blockIdx.x;
  const int c = threadIdx.x;  // 0..255 = channel
  __shared__ float red[4];
  __shared__ int s_valid[S_];
  for (int s = 0; s < S_; ++s) {
    float val;
    int pres;
    if (s < B_) {
      const unsigned cb = counts[s * K_ + k];
      val = sums[((size_t)s * K_ + k) * C_ + c] / fmaxf((float)cb, 1.f);
      pres = (cb > 0u) && (k >= 1);
    } else {
      val = prototypes[k * C_ + c];
      pres = (k >= 1);
    }
    float ss = val * val;
#pragma unroll
    for (int o = 32; o > 0; o >>= 1) ss += __shfl_down(ss, o);
    if ((c & 63) == 0) red[c >> 6] = ss;
    __syncthreads();
    const float tot = red[0] + red[1] + red[2] + red[3];
    const float nrm = fmaxf(sqrtf(tot), 1e-12f);
    Pm[((size_t)k * S_ + s) * C_ + c] = pres ? (val / nrm) * INV_SQRT_T : 0.f;
    if (c == 0) s_valid[s] = pres;
    __syncthreads();
  }
  if (c == 0) {
    int cnt = 0;
    for (int s = 0; s < S_; ++s) cnt += s_valid[s];
    const float cf = (float)cnt;
    cntk[k] = cf;
    const float wv = 1.f / fmaxf(cf, 1.f);
    for (int s = 0; s < S_; ++s) {
      valid[k * S_ + s] = s_valid[s];
      wcol[k * S_ + s] = s_valid[s] ? wv : 0.f;
    }
    if (cnt > 1 && k >= 1) atomAddGlb(&scal[1], 1.f);
  }
}

// ---------------------------------------------------------------------------
// K3: Gram matrix G = Pm * Pm^T  (already includes 1/T since Pm scaled).
// 128x128 tiles, 8x8 per thread, fp32 VALU. grid (14,14), block 256.
// ---------------------------------------------------------------------------
__global__ __launch_bounds__(256) void k_gram(const float* __restrict__ Pm,
                                              float* __restrict__ G) {
  __shared__ float As[32][132];
  __shared__ float Bs[32][132];
  const int j0 = blockIdx.x * 128, i0 = blockIdx.y * 128;
  const int tid = threadIdx.x;
  const int tx = tid & 15, ty = tid >> 4;
  float acc[8][8];
#pragma unroll
  for (int q = 0; q < 8; ++q)
#pragma unroll
    for (int r = 0; r < 8; ++r) acc[q][r] = 0.f;
  for (int kc = 0; kc < C_; kc += 32) {
#pragma unroll
    for (int q = 0; q < 4; ++q) {
      const int lin = tid + q * 256;
      const int r = lin >> 3, kk = (lin & 7) << 2;
      const float4 va = *(const float4*)&Pm[(size_t)(i0 + r) * C_ + kc + kk];
      As[kk + 0][r] = va.x; As[kk + 1][r] = va.y;
      As[kk + 2][r] = va.z; As[kk + 3][r] = va.w;
      const float4 vb = *(const float4*)&Pm[(size_t)(j0 + r) * C_ + kc + kk];
      Bs[kk + 0][r] = vb.x; Bs[kk + 1][r] = vb.y;
      Bs[kk + 2][r] = vb.z; Bs[kk + 3][r] = vb.w;
    }
    __syncthreads();
#pragma unroll
    for (int kk = 0; kk < 32; ++kk) {
      const float4 a0 = *(const float4*)&As[kk][ty * 8];
      const float4 a1 = *(const float4*)&As[kk][ty * 8 + 4];
      const float4 b0 = *(const float4*)&Bs[kk][tx * 8];
      const float4 b1 = *(const float4*)&Bs[kk][tx * 8 + 4];
      const float av[8] = {a0.x, a0.y, a0.z, a0.w, a1.x, a1.y, a1.z, a1.w};
      const float bv[8] = {b0.x, b0.y, b0.z, b0.w, b1.x, b1.y, b1.z, b1.w};
#pragma unroll
      for (int q = 0; q < 8; ++q)
#pragma unroll
        for (int r = 0; r < 8; ++r) acc[q][r] = fmaf(av[q], bv[r], acc[q][r]);
    }
    __syncthreads();
  }
#pragma unroll
  for (int q = 0; q < 8; ++q) {
    float4 o0 = {acc[q][0], acc[q][1], acc[q][2], acc[q][3]};
    float4 o1 = {acc[q][4], acc[q][5], acc[q][6], acc[q][7]};
    float* gr = &G[(size_t)(i0 + ty * 8 + q) * GN_ + j0 + tx * 8];
    *(float4*)gr = o0;
    *(float4*)(gr + 4) = o1;
  }
}

// ---------------------------------------------------------------------------
// K4: per-anchor loss. grid (16 slots, 101 classes), block 256.
// ---------------------------------------------------------------------------
__global__ __launch_bounds__(256) void k_loss(
    const float* __restrict__ G, const int* __restrict__ valid,
    const float* __restrict__ wcol, const float* __restrict__ cntk,
    float* __restrict__ scal) {
  const int s = blockIdx.x;  // 0..15 (batch slots only = anchors)
  const int k = blockIdx.y;  // 0..100
  const int a = k * S_ + s;
  if (!valid[a]) return;  // uniform over block
  const int tid = threadIdx.x;
  const float* row = G + (size_t)a * GN_;
  float dpart = 0.f;
  for (int j = tid; j < GN_; j += 256) dpart += wcol[j] * __expf(row[j]);
  __shared__ float red[4];
#pragma unroll
  for (int o = 32; o > 0; o >>= 1) dpart += __shfl_down(dpart, o);
  if ((tid & 63) == 0) red[tid >> 6] = dpart;
  __syncthreads();
  if (tid == 0) {
    const float den = red[0] + red[1] + red[2] + red[3];
    float pos = 0.f;
    for (int n = 0; n < S_; ++n)
      if (valid[k * S_ + n]) pos += row[k * S_ + n];
    pos -= row[a];  // remove self term (diag)
    const float np = cntk[k] - 1.f;
    const float npc = fmaxf(np, 1.f);
    const float pa = -(pos - np * logf(den)) / (npc * npc);
    atomAddGlb(&scal[0], pa);
  }
}

__global__ void k_final(const float* __restrict__ scal, float* __restrict__ out) {
  out[0] = 0.1f * scal[0] / scal[1];
}

// ---------------------------------------------------------------------------
extern "C" void kernel_launch(void* const* d_in, const int* in_sizes, int n_in,
                              void* d_out, int out_size, void* d_ws, size_t ws_size,
                              hipStream_t stream) {
  const int* labels = (const int*)d_in[0];
  const float* feats = (const float*)d_in[1];
  const float* protos = (const float*)d_in[2];
  float* out = (float*)d_out;

  char* wsb = (char*)d_ws;
  size_t o = 0;
  auto nxt = [&](size_t bytes) {
    size_t r = o;
    o = (o + bytes + 255) & ~(size_t)255;
    return r;
  };
  const size_t off_sums = nxt((size_t)B_ * K_ * C_ * 4);
  const size_t off_cnts = nxt((size_t)B_ * K_ * 4);
  const size_t off_P    = nxt((size_t)GN_ * C_ * 4);
  const size_t off_val  = nxt((size_t)GN_ * 4);
  const size_t off_w    = nxt((size_t)GN_ * 4);
  const size_t off_cntk = nxt((size_t)K_ * 4);
  const size_t off_scal = nxt(8);
  const size_t off_G    = nxt((size_t)GN_ * GN_ * 4);
  (void)off_G;

  float* w_sums    = (float*)(wsb + off_sums);
  unsigned* w_cnts = (unsigned*)(wsb + off_cnts);
  float* w_P       = (float*)(wsb + off_P);
  int* w_valid     = (int*)(wsb + off_val);
  float* w_w       = (float*)(wsb + off_w);
  float* w_cntk    = (float*)(wsb + off_cntk);
  float* w_scal    = (float*)(wsb + off_scal);
  float* w_G       = (float*)(wsb + off_G);

  // Zero everything before G (sums/counts/P-pad/valid/w/cntk/scalars).
  hipMemsetAsync(d_ws, 0, off_G, stream);

  k_segsum<<<512, 1024, 0, stream>>>(labels, feats, w_sums, w_cnts);
  k_protos<<<K_, 256, 0, stream>>>(w_sums, w_cnts, protos, w_P, w_valid, w_w,
                                   w_cntk, w_scal);
  k_gram<<<dim3(GN_ / 128, GN_ / 128), 256, 0, stream>>>(w_P, w_G);
  k_loss<<<dim3(B_, K_), 256, 0, stream>>>(w_G, w_valid, w_w, w_cntk, w_scal);
  k_final<<<1, 1, 0, stream>>>(w_scal, out);
}

// Round 3
// 434.453 us; speedup vs baseline: 1.6598x; 1.6598x over previous
//
#include <hip/hip_runtime.h>
#include <hip/hip_bf16.h>
#include <math.h>

// Problem constants (fixed by setup_inputs)
#define B_    16
#define C_    256
#define P_    16384          // 128*128
#define K_    101            // num_class + 1
#define S_    17             // B + 1 slots per class
#define V_    1717           // K_ * S_
#define GN_   1792           // V_ padded to 14*128
#define KPAD_ 102            // class stride in LDS (dummy slot for OOB labels)
#define SEG_  (128 * KPAD_)  // 13056 floats per (tile,q) partial slab
#define TEMP_ 0.07f
#define INV_SQRT_T 3.7796447300922720f   // 1/sqrt(0.07)

__device__ __forceinline__ void atomAddGlb(float* p, float v) {
  __hip_atomic_fetch_add(p, v, __ATOMIC_RELAXED, __HIP_MEMORY_SCOPE_AGENT);
}

// ---------------------------------------------------------------------------
// K1: per-(batch,class,tile) masked sums into private partial slabs (plain
// coalesced stores -- NO global atomics; the R2 profile showed the agent-scope
// atomic flush was the serialization point: 6.6M atomics ~ 4.4/cycle device-
// wide, VALUBusy 0.7%). grid 512 blocks x 1024.
// ---------------------------------------------------------------------------
__global__ __launch_bounds__(1024) void k_segsum(
    const int* __restrict__ labels, const float* __restrict__ feats,
    float* __restrict__ partial, unsigned* __restrict__ counts) {
  __shared__ float s_acc[SEG_];
  __shared__ int s_lab[1024];
  __shared__ unsigned s_cnt[KPAD_];
  const int id = blockIdx.x;
  const int q = id & 31;        // b*2 + zh
  const int tile = id >> 5;     // 0..15
  const int b = q >> 1, zh = q & 1;
  const int tid = threadIdx.x;
  for (int i = tid; i < SEG_; i += 1024) s_acc[i] = 0.f;
  if (zh == 0 && tid < KPAD_) s_cnt[tid] = 0u;
  const int p0 = tile * 1024;
  int lab = labels[b * P_ + p0 + tid];
  if ((unsigned)lab > 100u) lab = 101;  // route OOB labels to dummy slot
  s_lab[tid] = lab;
  __syncthreads();
  if (zh == 0) atomicAdd(&s_cnt[lab], 1u);
  const int wv = tid >> 6, ln = tid & 63;
  const float* fb = feats + ((size_t)b * C_ + (size_t)zh * 128) * P_ + p0;
  for (int g = 0; g < 4; ++g) {
    const int pb = g * 256 + ln * 4;
    const int4 lv = *(const int4*)&s_lab[pb];
#pragma unroll
    for (int j = 0; j < 8; ++j) {
      const int cl = wv * 8 + j;
      const float4 f = *(const float4*)&fb[(size_t)cl * P_ + pb];
      const int sA = cl * KPAD_;
      atomicAdd(&s_acc[sA + lv.x], f.x);
      atomicAdd(&s_acc[sA + lv.y], f.y);
      atomicAdd(&s_acc[sA + lv.z], f.z);
      atomicAdd(&s_acc[sA + lv.w], f.w);
    }
  }
  __syncthreads();
  // Plain coalesced dump of the whole accumulator (incl. dummy class slot).
  float* dst = partial + ((size_t)q * 16 + tile) * SEG_;
  for (int i = tid; i < SEG_; i += 1024) dst[i] = s_acc[i];
  if (zh == 0) {
    for (int i = tid; i < K_; i += 1024) {
      const unsigned cv = s_cnt[i];
      if (cv) atomicAdd(&counts[b * K_ + i], cv);
    }
  }
}

// ---------------------------------------------------------------------------
// K1b: reduce the 16 tile-slabs per (b,zh) with plain loads/stores.
// grid (13 chunks, 32 q), block 1024.
// ---------------------------------------------------------------------------
__global__ __launch_bounds__(1024) void k_reduce(
    const float* __restrict__ partial, float* __restrict__ sums) {
  const int q = blockIdx.y;
  const int b = q >> 1, zh = q & 1;
  const int idx = blockIdx.x * 1024 + threadIdx.x;
  if (idx >= SEG_) return;
  const int cl = idx / KPAD_, kk = idx - cl * KPAD_;
  const float* pb = partial + (size_t)q * 16 * SEG_ + idx;
  float s = 0.f;
#pragma unroll
  for (int t = 0; t < 16; ++t) s += pb[(size_t)t * SEG_];
  if (kk < K_) sums[((size_t)b * K_ + kk) * C_ + zh * 128 + cl] = s;
}

// ---------------------------------------------------------------------------
// K2: build normalized prototype slots (pre-scaled by 1/sqrt(T)), valid mask,
// per-class cnt, per-column weight, cnt_exist. grid K_ blocks, 256 threads.
// ---------------------------------------------------------------------------
__global__ __launch_bounds__(256) void k_protos(
    const float* __restrict__ sums, const unsigned* __restrict__ counts,
    const float* __restrict__ prototypes, float* __restrict__ Pm,
    int* __restrict__ valid, float* __restrict__ wcol,
    float* __restrict__ cntk, float* __restrict__ scal) {
  const int k = blockIdx.x;
  const int c = threadIdx.x;  // 0..255 = channel
  __shared__ float red[4];
  __shared__ int s_valid[S_];
  for (int s = 0; s < S_; ++s) {
    float val;
    int pres;
    if (s < B_) {
      const unsigned cb = counts[s * K_ + k];
      val = sums[((size_t)s * K_ + k) * C_ + c] / fmaxf((float)cb, 1.f);
      pres = (cb > 0u) && (k >= 1);
    } else {
      val = prototypes[k * C_ + c];
      pres = (k >= 1);
    }
    float ss = val * val;
#pragma unroll
    for (int o = 32; o > 0; o >>= 1) ss += __shfl_down(ss, o);
    if ((c & 63) == 0) red[c >> 6] = ss;
    __syncthreads();
    const float tot = red[0] + red[1] + red[2] + red[3];
    const float nrm = fmaxf(sqrtf(tot), 1e-12f);
    Pm[((size_t)k * S_ + s) * C_ + c] = pres ? (val / nrm) * INV_SQRT_T : 0.f;
    if (c == 0) s_valid[s] = pres;
    __syncthreads();
  }
  if (c == 0) {
    int cnt = 0;
    for (int s = 0; s < S_; ++s) cnt += s_valid[s];
    const float cf = (float)cnt;
    cntk[k] = cf;
    const float wv = 1.f / fmaxf(cf, 1.f);
    for (int s = 0; s < S_; ++s) {
      valid[k * S_ + s] = s_valid[s];
      wcol[k * S_ + s] = s_valid[s] ? wv : 0.f;
    }
    if (cnt > 1 && k >= 1) atomAddGlb(&scal[1], 1.f);
  }
}

// ---------------------------------------------------------------------------
// K3: Gram matrix G = Pm * Pm^T  (already includes 1/T since Pm scaled).
// 128x128 tiles, 8x8 per thread, fp32 VALU. grid (14,14), block 256.
// ---------------------------------------------------------------------------
__global__ __launch_bounds__(256) void k_gram(const float* __restrict__ Pm,
                                              float* __restrict__ G) {
  __shared__ float As[32][132];
  __shared__ float Bs[32][132];
  const int j0 = blockIdx.x * 128, i0 = blockIdx.y * 128;
  const int tid = threadIdx.x;
  const int tx = tid & 15, ty = tid >> 4;
  float acc[8][8];
#pragma unroll
  for (int q = 0; q < 8; ++q)
#pragma unroll
    for (int r = 0; r < 8; ++r) acc[q][r] = 0.f;
  for (int kc = 0; kc < C_; kc += 32) {
#pragma unroll
    for (int q = 0; q < 4; ++q) {
      const int lin = tid + q * 256;
      const int r = lin >> 3, kk = (lin & 7) << 2;
      const float4 va = *(const float4*)&Pm[(size_t)(i0 + r) * C_ + kc + kk];
      As[kk + 0][r] = va.x; As[kk + 1][r] = va.y;
      As[kk + 2][r] = va.z; As[kk + 3][r] = va.w;
      const float4 vb = *(const float4*)&Pm[(size_t)(j0 + r) * C_ + kc + kk];
      Bs[kk + 0][r] = vb.x; Bs[kk + 1][r] = vb.y;
      Bs[kk + 2][r] = vb.z; Bs[kk + 3][r] = vb.w;
    }
    __syncthreads();
#pragma unroll
    for (int kk = 0; kk < 32; ++kk) {
      const float4 a0 = *(const float4*)&As[kk][ty * 8];
      const float4 a1 = *(const float4*)&As[kk][ty * 8 + 4];
      const float4 b0 = *(const float4*)&Bs[kk][tx * 8];
      const float4 b1 = *(const float4*)&Bs[kk][tx * 8 + 4];
      const float av[8] = {a0.x, a0.y, a0.z, a0.w, a1.x, a1.y, a1.z, a1.w};
      const float bv[8] = {b0.x, b0.y, b0.z, b0.w, b1.x, b1.y, b1.z, b1.w};
#pragma unroll
      for (int q = 0; q < 8; ++q)
#pragma unroll
        for (int r = 0; r < 8; ++r) acc[q][r] = fmaf(av[q], bv[r], acc[q][r]);
    }
    __syncthreads();
  }
#pragma unroll
  for (int q = 0; q < 8; ++q) {
    float4 o0 = {acc[q][0], acc[q][1], acc[q][2], acc[q][3]};
    float4 o1 = {acc[q][4], acc[q][5], acc[q][6], acc[q][7]};
    float* gr = &G[(size_t)(i0 + ty * 8 + q) * GN_ + j0 + tx * 8];
    *(float4*)gr = o0;
    *(float4*)(gr + 4) = o1;
  }
}

// ---------------------------------------------------------------------------
// K4: per-anchor loss. grid (16 slots, 101 classes), block 256.
// ---------------------------------------------------------------------------
__global__ __launch_bounds__(256) void k_loss(
    const float* __restrict__ G, const int* __restrict__ valid,
    const float* __restrict__ wcol, const float* __restrict__ cntk,
    float* __restrict__ scal) {
  const int s = blockIdx.x;  // 0..15 (batch slots only = anchors)
  const int k = blockIdx.y;  // 0..100
  const int a = k * S_ + s;
  if (!valid[a]) return;  // uniform over block
  const int tid = threadIdx.x;
  const float* row = G + (size_t)a * GN_;
  float dpart = 0.f;
  for (int j = tid; j < GN_; j += 256) dpart += wcol[j] * __expf(row[j]);
  __shared__ float red[4];
#pragma unroll
  for (int o = 32; o > 0; o >>= 1) dpart += __shfl_down(dpart, o);
  if ((tid & 63) == 0) red[tid >> 6] = dpart;
  __syncthreads();
  if (tid == 0) {
    const float den = red[0] + red[1] + red[2] + red[3];
    float pos = 0.f;
    for (int n = 0; n < S_; ++n)
      if (valid[k * S_ + n]) pos += row[k * S_ + n];
    pos -= row[a];  // remove self term (diag)
    const float np = cntk[k] - 1.f;
    const float npc = fmaxf(np, 1.f);
    const float pa = -(pos - np * logf(den)) / (npc * npc);
    atomAddGlb(&scal[0], pa);
  }
}

__global__ void k_final(const float* __restrict__ scal, float* __restrict__ out) {
  out[0] = 0.1f * scal[0] / scal[1];
}

// ---------------------------------------------------------------------------
extern "C" void kernel_launch(void* const* d_in, const int* in_sizes, int n_in,
                              void* d_out, int out_size, void* d_ws, size_t ws_size,
                              hipStream_t stream) {
  const int* labels = (const int*)d_in[0];
  const float* feats = (const float*)d_in[1];
  const float* protos = (const float*)d_in[2];
  float* out = (float*)d_out;

  char* wsb = (char*)d_ws;
  size_t o = 0;
  auto nxt = [&](size_t bytes) {
    size_t r = o;
    o = (o + bytes + 255) & ~(size_t)255;
    return r;
  };
  // Small region (memset each call):
  const size_t off_sums = nxt((size_t)B_ * K_ * C_ * 4);
  const size_t off_cnts = nxt((size_t)B_ * K_ * 4);
  const size_t off_P    = nxt((size_t)GN_ * C_ * 4);
  const size_t off_val  = nxt((size_t)GN_ * 4);
  const size_t off_w    = nxt((size_t)GN_ * 4);
  const size_t off_cntk = nxt((size_t)K_ * 4);
  const size_t off_scal = nxt(8);
  const size_t small_end = o;
  // Big region: partial slabs and G share storage (disjoint lifetimes).
  const size_t partial_bytes = (size_t)32 * 16 * SEG_ * 4;   // 26.7 MB
  const size_t g_bytes = (size_t)GN_ * GN_ * 4;              // 12.8 MB
  const size_t off_big = nxt(partial_bytes > g_bytes ? partial_bytes : g_bytes);

  float* w_sums    = (float*)(wsb + off_sums);
  unsigned* w_cnts = (unsigned*)(wsb + off_cnts);
  float* w_P       = (float*)(wsb + off_P);
  int* w_valid     = (int*)(wsb + off_val);
  float* w_w       = (float*)(wsb + off_w);
  float* w_cntk    = (float*)(wsb + off_cntk);
  float* w_scal    = (float*)(wsb + off_scal);
  float* w_partial = (float*)(wsb + off_big);
  float* w_G       = (float*)(wsb + off_big);

  // Zero the small region (counts accumulated by atomics, Pm/wcol pad tails,
  // scalars). partial/G are fully overwritten by their producers.
  hipMemsetAsync(d_ws, 0, small_end, stream);

  k_segsum<<<512, 1024, 0, stream>>>(labels, feats, w_partial, w_cnts);
  k_reduce<<<dim3(13, 32), 1024, 0, stream>>>(w_partial, w_sums);
  k_protos<<<K_, 256, 0, stream>>>(w_sums, w_cnts, protos, w_P, w_valid, w_w,
                                   w_cntk, w_scal);
  k_gram<<<dim3(GN_ / 128, GN_ / 128), 256, 0, stream>>>(w_P, w_G);
  k_loss<<<dim3(B_, K_), 256, 0, stream>>>(w_G, w_valid, w_w, w_cntk, w_scal);
  k_final<<<1, 1, 0, stream>>>(w_scal, out);
}

// Round 4
// 366.864 us; speedup vs baseline: 1.9656x; 1.1842x over previous
//
#include <hip/hip_runtime.h>
#include <hip/hip_bf16.h>
#include <math.h>

// Problem constants (fixed by setup_inputs)
#define B_    16
#define C_    256
#define P_    16384          // 128*128
#define K_    101            // num_class + 1
#define S_    17             // B + 1 slots per class
#define V_    1717           // K_ * S_
#define GN_   1792           // V_ padded to 14*128
#define MCLS_ 112            // class dim padded to 7 MFMA tiles of 16
#define TEMP_ 0.07f
#define INV_SQRT_T 3.7796447300922720f   // 1/sqrt(0.07)

typedef __bf16 bf16x8 __attribute__((ext_vector_type(8)));
typedef float f32x4 __attribute__((ext_vector_type(4)));
typedef int   i32x4 __attribute__((ext_vector_type(4)));

__device__ __forceinline__ void atomAddGlb(float* p, float v) {
  __hip_atomic_fetch_add(p, v, __ATOMIC_RELAXED, __HIP_MEMORY_SCOPE_AGENT);
}

// ---------------------------------------------------------------------------
// K1: segmented sums via MFMA.  D[cls][ch] += onehot[cls][px] * feats[px][ch]
// with fp32 feats split into exact bf16 hi/lo pairs (both accumulated into
// the same fp32 acc).  R3 showed the LDS fp32-atomic pipe (~2cyc/lane) was
// the 341us floor -- this removes LDS atomics from the feature path entirely.
// Blocks 0..255: (b = id&15, chgroup = (id>>4)&3, pxquarter = id>>6), 256 thr
//   = 4 waves; each wave owns 16 channels and a private LDS slice+label copy
//   -> completely barrier-free main loop (same-wave DS ops are ordered).
// Blocks 256..271: per-batch label histogram (runs concurrently).
// ---------------------------------------------------------------------------
__global__ __launch_bounds__(256) void k_segsum(
    const int* __restrict__ labels, const float* __restrict__ feats,
    float* __restrict__ psum, unsigned* __restrict__ counts) {
  __shared__ unsigned s_hi[64 * 68];   // [ch 0..63][68 dw], 64 dw = 128 px pairs
  __shared__ unsigned s_lo[64 * 68];
  __shared__ int s_lab[4 * 128];       // per-wave private label copy
  __shared__ unsigned s_cnt[102];
  const int id = blockIdx.x;
  const int tid = threadIdx.x;

  if (id >= 256) {  // ---- label counts for batch id-256 ----
    const int b = id - 256;
    if (tid < 102) s_cnt[tid] = 0u;
    __syncthreads();
    for (int i = 0; i < 64; ++i) {
      int lab = labels[b * P_ + i * 256 + tid];
      if ((unsigned)lab > 100u) lab = 101;
      atomicAdd(&s_cnt[lab], 1u);
    }
    __syncthreads();
    if (tid < K_) counts[b * K_ + tid] = s_cnt[tid];
    return;
  }

  const int b = id & 15, cg = (id >> 4) & 3, pq = id >> 6;
  const int wv = tid >> 6, ln = tid & 63;
  const int lg = ln >> 4;    // lane group 0..3 (k-window selector)
  const int lc = ln & 15;    // lane-in-group: A row (class) / B col (channel)
  const int c0 = cg * 64;
  const int pbase = pq * 4096;

  f32x4 acc[7];
#pragma unroll
  for (int t = 0; t < 7; ++t) acc[t] = (f32x4)0.f;

  for (int cc = 0; cc < 32; ++cc) {
    const int pc = pbase + cc * 128;
    // stage this wave's private label copy (128 px)
    s_lab[wv * 128 + ln] = labels[b * P_ + pc + ln];
    s_lab[wv * 128 + 64 + ln] = labels[b * P_ + pc + 64 + ln];
    // stage this wave's 16 channels as packed bf16 hi/lo pairs
#pragma unroll
    for (int i = 0; i < 16; ++i) {
      const int ch = c0 + wv * 16 + i;
      const float2 f =
          *(const float2*)&feats[((size_t)b * C_ + ch) * P_ + pc + 2 * ln];
      const unsigned u0 = __float_as_uint(f.x), u1 = __float_as_uint(f.y);
      const unsigned hi = (u0 >> 16) | (u1 & 0xFFFF0000u);
      const float h0 = __uint_as_float(u0 & 0xFFFF0000u);
      const float h1 = __uint_as_float(u1 & 0xFFFF0000u);
      const unsigned v0 = __float_as_uint(f.x - h0);
      const unsigned v1 = __float_as_uint(f.y - h1);
      const unsigned lo = (v0 >> 16) | (v1 & 0xFFFF0000u);
      const int rowbase = (wv * 16 + i) * 68;
      s_hi[rowbase + ln] = hi;
      s_lo[rowbase + ln] = lo;
    }
    // no __syncthreads: each wave reads only rows/labels it wrote itself.
#pragma unroll
    for (int ks = 0; ks < 4; ++ks) {
      // labels of this lane-group's 8-pixel k-window
      const i32x4 la = *(const i32x4*)&s_lab[wv * 128 + ks * 32 + lg * 8];
      const i32x4 lb = *(const i32x4*)&s_lab[wv * 128 + ks * 32 + lg * 8 + 4];
      int labc[8];
      labc[0] = la.x - lc; labc[1] = la.y - lc;
      labc[2] = la.z - lc; labc[3] = la.w - lc;
      labc[4] = lb.x - lc; labc[5] = lb.y - lc;
      labc[6] = lb.z - lc; labc[7] = lb.w - lc;
      // B fragments: 8 px of this lane's channel, hi and lo planes
      const int baddr = (wv * 16 + lc) * 68 + ks * 16 + lg * 4;
      const bf16x8 bh = __builtin_bit_cast(bf16x8, *(const i32x4*)&s_hi[baddr]);
      const bf16x8 bl = __builtin_bit_cast(bf16x8, *(const i32x4*)&s_lo[baddr]);
#pragma unroll
      for (int t = 0; t < 7; ++t) {
        const int m0 = t * 16;
        i32x4 av;
#pragma unroll
        for (int r = 0; r < 4; ++r) {
          unsigned v = (labc[2 * r] == m0) ? 0x3F80u : 0u;
          if (labc[2 * r + 1] == m0) v |= 0x3F800000u;
          av[r] = (int)v;
        }
        const bf16x8 af = __builtin_bit_cast(bf16x8, av);
        acc[t] = __builtin_amdgcn_mfma_f32_16x16x32_bf16(af, bh, acc[t], 0, 0, 0);
        acc[t] = __builtin_amdgcn_mfma_f32_16x16x32_bf16(af, bl, acc[t], 0, 0, 0);
      }
    }
  }
  // epilogue: D row = t*16 + lg*4 + r (class), col = lc (channel)
  float* pout =
      psum + (((size_t)pq * 16 + b) * MCLS_) * 256 + c0 + wv * 16 + lc;
#pragma unroll
  for (int t = 0; t < 7; ++t)
#pragma unroll
    for (int r = 0; r < 4; ++r)
      pout[(size_t)(t * 16 + lg * 4 + r) * 256] = acc[t][r];
}

// ---------------------------------------------------------------------------
// K1b: reduce the 4 pixel-quarter partials -> sums[b][k][c].
// ---------------------------------------------------------------------------
__global__ __launch_bounds__(256) void k_reduce(const float* __restrict__ psum,
                                                float* __restrict__ sums) {
  const int id = blockIdx.x * 256 + threadIdx.x;
  if (id >= B_ * K_ * C_) return;
  const int c = id & 255;
  const int rem = id >> 8;
  const int k = rem % K_;
  const int b = rem / K_;
  float s = 0.f;
#pragma unroll
  for (int pq = 0; pq < 4; ++pq)
    s += psum[(((size_t)pq * 16 + b) * MCLS_ + k) * 256 + c];
  sums[((size_t)b * K_ + k) * C_ + c] = s;
}

// ---------------------------------------------------------------------------
// K2: build normalized prototype slots (pre-scaled by 1/sqrt(T)), valid mask,
// per-class cnt, per-column weight, cnt_exist. grid K_ blocks, 256 threads.
// ---------------------------------------------------------------------------
__global__ __launch_bounds__(256) void k_protos(
    const float* __restrict__ sums, const unsigned* __restrict__ counts,
    const float* __restrict__ prototypes, float* __restrict__ Pm,
    int* __restrict__ valid, float* __restrict__ wcol,
    float* __restrict__ cntk, float* __restrict__ scal) {
  const int k = blockIdx.x;
  const int c = threadIdx.x;  // 0..255 = channel
  __shared__ float red[4];
  __shared__ int s_valid[S_];
  for (int s = 0; s < S_; ++s) {
    float val;
    int pres;
    if (s < B_) {
      const unsigned cb = counts[s * K_ + k];
      val = sums[((size_t)s * K_ + k) * C_ + c] / fmaxf((float)cb, 1.f);
      pres = (cb > 0u) && (k >= 1);
    } else {
      val = prototypes[k * C_ + c];
      pres = (k >= 1);
    }
    float ss = val * val;
#pragma unroll
    for (int o = 32; o > 0; o >>= 1) ss += __shfl_down(ss, o);
    if ((c & 63) == 0) red[c >> 6] = ss;
    __syncthreads();
    const float tot = red[0] + red[1] + red[2] + red[3];
    const float nrm = fmaxf(sqrtf(tot), 1e-12f);
    Pm[((size_t)k * S_ + s) * C_ + c] = pres ? (val / nrm) * INV_SQRT_T : 0.f;
    if (c == 0) s_valid[s] = pres;
    __syncthreads();
  }
  if (c == 0) {
    int cnt = 0;
    for (int s = 0; s < S_; ++s) cnt += s_valid[s];
    const float cf = (float)cnt;
    cntk[k] = cf;
    const float wv = 1.f / fmaxf(cf, 1.f);
    for (int s = 0; s < S_; ++s) {
      valid[k * S_ + s] = s_valid[s];
      wcol[k * S_ + s] = s_valid[s] ? wv : 0.f;
    }
    if (cnt > 1 && k >= 1) atomAddGlb(&scal[1], 1.f);
  }
}

// ---------------------------------------------------------------------------
// K3: Gram matrix G = Pm * Pm^T  (already includes 1/T since Pm scaled).
// 128x128 tiles, 8x8 per thread, fp32 VALU. grid (14,14), block 256.
// ---------------------------------------------------------------------------
__global__ __launch_bounds__(256) void k_gram(const float* __restrict__ Pm,
                                              float* __restrict__ G) {
  __shared__ float As[32][132];
  __shared__ float Bs[32][132];
  const int j0 = blockIdx.x * 128, i0 = blockIdx.y * 128;
  const int tid = threadIdx.x;
  const int tx = tid & 15, ty = tid >> 4;
  float acc[8][8];
#pragma unroll
  for (int q = 0; q < 8; ++q)
#pragma unroll
    for (int r = 0; r < 8; ++r) acc[q][r] = 0.f;
  for (int kc = 0; kc < C_; kc += 32) {
#pragma unroll
    for (int q = 0; q < 4; ++q) {
      const int lin = tid + q * 256;
      const int r = lin >> 3, kk = (lin & 7) << 2;
      const float4 va = *(const float4*)&Pm[(size_t)(i0 + r) * C_ + kc + kk];
      As[kk + 0][r] = va.x; As[kk + 1][r] = va.y;
      As[kk + 2][r] = va.z; As[kk + 3][r] = va.w;
      const float4 vb = *(const float4*)&Pm[(size_t)(j0 + r) * C_ + kc + kk];
      Bs[kk + 0][r] = vb.x; Bs[kk + 1][r] = vb.y;
      Bs[kk + 2][r] = vb.z; Bs[kk + 3][r] = vb.w;
    }
    __syncthreads();
#pragma unroll
    for (int kk = 0; kk < 32; ++kk) {
      const float4 a0 = *(const float4*)&As[kk][ty * 8];
      const float4 a1 = *(const float4*)&As[kk][ty * 8 + 4];
      const float4 b0 = *(const float4*)&Bs[kk][tx * 8];
      const float4 b1 = *(const float4*)&Bs[kk][tx * 8 + 4];
      const float av[8] = {a0.x, a0.y, a0.z, a0.w, a1.x, a1.y, a1.z, a1.w};
      const float bv[8] = {b0.x, b0.y, b0.z, b0.w, b1.x, b1.y, b1.z, b1.w};
#pragma unroll
      for (int q = 0; q < 8; ++q)
#pragma unroll
        for (int r = 0; r < 8; ++r) acc[q][r] = fmaf(av[q], bv[r], acc[q][r]);
    }
    __syncthreads();
  }
#pragma unroll
  for (int q = 0; q < 8; ++q) {
    float4 o0 = {acc[q][0], acc[q][1], acc[q][2], acc[q][3]};
    float4 o1 = {acc[q][4], acc[q][5], acc[q][6], acc[q][7]};
    float* gr = &G[(size_t)(i0 + ty * 8 + q) * GN_ + j0 + tx * 8];
    *(float4*)gr = o0;
    *(float4*)(gr + 4) = o1;
  }
}

// ---------------------------------------------------------------------------
// K4: per-anchor loss. grid (16 slots, 101 classes), block 256.
// ---------------------------------------------------------------------------
__global__ __launch_bounds__(256) void k_loss(
    const float* __restrict__ G, const int* __restrict__ valid,
    const float* __restrict__ wcol, const float* __restrict__ cntk,
    float* __restrict__ scal) {
  const int s = blockIdx.x;  // 0..15 (batch slots only = anchors)
  const int k = blockIdx.y;  // 0..100
  const int a = k * S_ + s;
  if (!valid[a]) return;  // uniform over block
  const int tid = threadIdx.x;
  const float* row = G + (size_t)a * GN_;
  float dpart = 0.f;
  for (int j = tid; j < GN_; j += 256) dpart += wcol[j] * __expf(row[j]);
  __shared__ float red[4];
#pragma unroll
  for (int o = 32; o > 0; o >>= 1) dpart += __shfl_down(dpart, o);
  if ((tid & 63) == 0) red[tid >> 6] = dpart;
  __syncthreads();
  if (tid == 0) {
    const float den = red[0] + red[1] + red[2] + red[3];
    float pos = 0.f;
    for (int n = 0; n < S_; ++n)
      if (valid[k * S_ + n]) pos += row[k * S_ + n];
    pos -= row[a];  // remove self term (diag)
    const float np = cntk[k] - 1.f;
    const float npc = fmaxf(np, 1.f);
    const float pa = -(pos - np * logf(den)) / (npc * npc);
    atomAddGlb(&scal[0], pa);
  }
}

__global__ void k_final(const float* __restrict__ scal, float* __restrict__ out) {
  out[0] = 0.1f * scal[0] / scal[1];
}

// ---------------------------------------------------------------------------
extern "C" void kernel_launch(void* const* d_in, const int* in_sizes, int n_in,
                              void* d_out, int out_size, void* d_ws, size_t ws_size,
                              hipStream_t stream) {
  const int* labels = (const int*)d_in[0];
  const float* feats = (const float*)d_in[1];
  const float* protos = (const float*)d_in[2];
  float* out = (float*)d_out;

  char* wsb = (char*)d_ws;
  size_t o = 0;
  auto nxt = [&](size_t bytes) {
    size_t r = o;
    o = (o + bytes + 255) & ~(size_t)255;
    return r;
  };
  // Small region (memset each call):
  const size_t off_sums = nxt((size_t)B_ * K_ * C_ * 4);
  const size_t off_cnts = nxt((size_t)B_ * K_ * 4);
  const size_t off_P    = nxt((size_t)GN_ * C_ * 4);
  const size_t off_val  = nxt((size_t)GN_ * 4);
  const size_t off_w    = nxt((size_t)GN_ * 4);
  const size_t off_cntk = nxt((size_t)K_ * 4);
  const size_t off_scal = nxt(8);
  const size_t small_end = o;
  // Big region: psum partials and G share storage (disjoint lifetimes).
  const size_t psum_bytes = (size_t)4 * 16 * MCLS_ * 256 * 4;  // 7.34 MB
  const size_t g_bytes = (size_t)GN_ * GN_ * 4;                // 12.8 MB
  const size_t off_big = nxt(psum_bytes > g_bytes ? psum_bytes : g_bytes);

  float* w_sums    = (float*)(wsb + off_sums);
  unsigned* w_cnts = (unsigned*)(wsb + off_cnts);
  float* w_P       = (float*)(wsb + off_P);
  int* w_valid     = (int*)(wsb + off_val);
  float* w_w       = (float*)(wsb + off_w);
  float* w_cntk    = (float*)(wsb + off_cntk);
  float* w_scal    = (float*)(wsb + off_scal);
  float* w_psum    = (float*)(wsb + off_big);
  float* w_G       = (float*)(wsb + off_big);

  // Zero the small region (Pm pad rows feed k_gram; scalars accumulate).
  hipMemsetAsync(d_ws, 0, small_end, stream);

  k_segsum<<<272, 256, 0, stream>>>(labels, feats, w_psum, w_cnts);
  k_reduce<<<(B_ * K_ * C_ + 255) / 256, 256, 0, stream>>>(w_psum, w_sums);
  k_protos<<<K_, 256, 0, stream>>>(w_sums, w_cnts, protos, w_P, w_valid, w_w,
                                   w_cntk, w_scal);
  k_gram<<<dim3(GN_ / 128, GN_ / 128), 256, 0, stream>>>(w_P, w_G);
  k_loss<<<dim3(B_, K_), 256, 0, stream>>>(w_G, w_valid, w_w, w_cntk, w_scal);
  k_final<<<1, 1, 0, stream>>>(w_scal, out);
}

// Round 5
// 166.443 us; speedup vs baseline: 4.3324x; 2.2041x over previous
//
#include <hip/hip_runtime.h>
#include <hip/hip_bf16.h>
#include <math.h>

// Problem constants (fixed by setup_inputs)
#define B_    16
#define C_    256
#define P_    16384          // 128*128
#define K_    101            // num_class + 1
#define S_    17             // B + 1 slots per class
#define V_    1717           // K_ * S_
#define GN_   1792           // V_ padded to 14*128
#define NPQ_  16             // pixel-slice partials
#define TEMP_ 0.07f
#define INV_SQRT_T 3.7796447300922720f   // 1/sqrt(0.07)

typedef __bf16 bf16x8 __attribute__((ext_vector_type(8)));
typedef float f32x4 __attribute__((ext_vector_type(4)));
typedef int   i32x4 __attribute__((ext_vector_type(4)));

__device__ __forceinline__ void atomAddGlb(float* p, float v) {
  __hip_atomic_fetch_add(p, v, __ATOMIC_RELAXED, __HIP_MEMORY_SCOPE_AGENT);
}

// ---------------------------------------------------------------------------
// K1: segmented sums via MFMA, zero LDS on the feature path.
// R4 failed on occupancy (256 blocks = 1 wave/SIMD, latency-exposed).  Now:
// grid 1024 blocks x 256 thr (= 4096 working waves), each wave owns
// (b, 16-channel group cg, 1024-px slice pq) and streams B-fragments straight
// from global (2x float4 per lane), A-fragments from labels (2x int4).
// fp32 features split exactly into bf16 hi+lo, both MFMA'd into fp32 acc.
// Blocks 1024..1039: per-batch label histogram.
// ---------------------------------------------------------------------------
__global__ __launch_bounds__(256, 4) void k_segsum(
    const int* __restrict__ labels, const float* __restrict__ feats,
    float* __restrict__ psum, unsigned* __restrict__ counts) {
  __shared__ unsigned s_cnt[102];
  const int id = blockIdx.x;
  const int tid = threadIdx.x;

  if (id >= 1024) {  // ---- label counts for batch id-1024 ----
    const int b = id - 1024;
    if (tid < 102) s_cnt[tid] = 0u;
    __syncthreads();
    for (int i = 0; i < 64; ++i) {
      int lab = labels[b * P_ + i * 256 + tid];
      if ((unsigned)lab > 100u) lab = 101;
      atomicAdd(&s_cnt[lab], 1u);
    }
    __syncthreads();
    if (tid < K_) counts[b * K_ + tid] = s_cnt[tid];
    return;
  }

  // cg innermost so the 16 blocks sharing (b,pqg) labels are dispatch-adjacent
  const int cg = id & 15, pqg = (id >> 4) & 3, b = id >> 6;
  const int wv = tid >> 6, ln = tid & 63;
  const int lg = ln >> 4;    // lane group 0..3 (k-window selector)
  const int lc = ln & 15;    // lane-in-group: A row (class) / B col (channel)
  const int pq = pqg * 4 + wv;
  const int ch = cg * 16 + lc;
  const int pbase = pq * 1024;
  const int* lrow = labels + b * P_ + pbase + lg * 8;
  const float* frow = feats + ((size_t)b * C_ + ch) * P_ + pbase + lg * 8;

  f32x4 acc[7];
#pragma unroll
  for (int t = 0; t < 7; ++t) acc[t] = (f32x4)0.f;

  for (int w = 0; w < 32; ++w) {
    const int off = w * 32;
    const i32x4 la = *(const i32x4*)&lrow[off];
    const i32x4 lb = *(const i32x4*)&lrow[off + 4];
    const float4 f0 = *(const float4*)&frow[off];
    const float4 f1 = *(const float4*)&frow[off + 4];
    // exact fp32 -> bf16 hi/lo split, packed 2 px per dword (even px = low)
    i32x4 hid, lod;
    {
      const float fx[8] = {f0.x, f0.y, f0.z, f0.w, f1.x, f1.y, f1.z, f1.w};
#pragma unroll
      for (int p2 = 0; p2 < 4; ++p2) {
        const unsigned u0 = __float_as_uint(fx[2 * p2]);
        const unsigned u1 = __float_as_uint(fx[2 * p2 + 1]);
        hid[p2] = (int)((u0 >> 16) | (u1 & 0xFFFF0000u));
        const float h0 = __uint_as_float(u0 & 0xFFFF0000u);
        const float h1 = __uint_as_float(u1 & 0xFFFF0000u);
        const unsigned v0 = __float_as_uint(fx[2 * p2] - h0);
        const unsigned v1 = __float_as_uint(fx[2 * p2 + 1] - h1);
        lod[p2] = (int)((v0 >> 16) | (v1 & 0xFFFF0000u));
      }
    }
    const bf16x8 bh = __builtin_bit_cast(bf16x8, hid);
    const bf16x8 bl = __builtin_bit_cast(bf16x8, lod);
    int d[8];
    d[0] = la.x - lc; d[1] = la.y - lc; d[2] = la.z - lc; d[3] = la.w - lc;
    d[4] = lb.x - lc; d[5] = lb.y - lc; d[6] = lb.z - lc; d[7] = lb.w - lc;
#pragma unroll
    for (int t = 0; t < 7; ++t) {
      const int m0 = t * 16;
      i32x4 av;
#pragma unroll
      for (int r = 0; r < 4; ++r) {
        unsigned v = (d[2 * r] == m0) ? 0x3F80u : 0u;
        if (d[2 * r + 1] == m0) v |= 0x3F800000u;
        av[r] = (int)v;
      }
      const bf16x8 af = __builtin_bit_cast(bf16x8, av);
      acc[t] = __builtin_amdgcn_mfma_f32_16x16x32_bf16(af, bh, acc[t], 0, 0, 0);
      acc[t] = __builtin_amdgcn_mfma_f32_16x16x32_bf16(af, bl, acc[t], 0, 0, 0);
    }
  }
  // epilogue: D row = t*16 + lg*4 + r (class), col = lc (channel)
  float* pout = psum + (((size_t)pq * 16 + b) * K_) * 256 + cg * 16 + lc;
#pragma unroll
  for (int t = 0; t < 7; ++t)
#pragma unroll
    for (int r = 0; r < 4; ++r) {
      const int row = t * 16 + lg * 4 + r;
      if (row < K_) pout[(size_t)row * 256] = acc[t][r];
    }
}

// ---------------------------------------------------------------------------
// K1b: reduce the 16 pixel-slice partials -> sums[b][k][c].
// ---------------------------------------------------------------------------
__global__ __launch_bounds__(256) void k_reduce(const float* __restrict__ psum,
                                                float* __restrict__ sums) {
  const int id = blockIdx.x * 256 + threadIdx.x;
  if (id >= B_ * K_ * C_) return;
  const int c = id & 255;
  const int rem = id >> 8;
  const int k = rem % K_;
  const int b = rem / K_;
  float s = 0.f;
#pragma unroll
  for (int pq = 0; pq < NPQ_; ++pq)
    s += psum[(((size_t)pq * 16 + b) * K_ + k) * 256 + c];
  sums[((size_t)b * K_ + k) * C_ + c] = s;
}

// ---------------------------------------------------------------------------
// K2: build normalized prototype slots (pre-scaled by 1/sqrt(T)), valid mask,
// per-class cnt, per-column weight, cnt_exist. grid K_ blocks, 256 threads.
// ---------------------------------------------------------------------------
__global__ __launch_bounds__(256) void k_protos(
    const float* __restrict__ sums, const unsigned* __restrict__ counts,
    const float* __restrict__ prototypes, float* __restrict__ Pm,
    int* __restrict__ valid, float* __restrict__ wcol,
    float* __restrict__ cntk, float* __restrict__ scal) {
  const int k = blockIdx.x;
  const int c = threadIdx.x;  // 0..255 = channel
  __shared__ float red[4];
  __shared__ int s_valid[S_];
  for (int s = 0; s < S_; ++s) {
    float val;
    int pres;
    if (s < B_) {
      const unsigned cb = counts[s * K_ + k];
      val = sums[((size_t)s * K_ + k) * C_ + c] / fmaxf((float)cb, 1.f);
      pres = (cb > 0u) && (k >= 1);
    } else {
      val = prototypes[k * C_ + c];
      pres = (k >= 1);
    }
    float ss = val * val;
#pragma unroll
    for (int o = 32; o > 0; o >>= 1) ss += __shfl_down(ss, o);
    if ((c & 63) == 0) red[c >> 6] = ss;
    __syncthreads();
    const float tot = red[0] + red[1] + red[2] + red[3];
    const float nrm = fmaxf(sqrtf(tot), 1e-12f);
    Pm[((size_t)k * S_ + s) * C_ + c] = pres ? (val / nrm) * INV_SQRT_T : 0.f;
    if (c == 0) s_valid[s] = pres;
    __syncthreads();
  }
  if (c == 0) {
    int cnt = 0;
    for (int s = 0; s < S_; ++s) cnt += s_valid[s];
    const float cf = (float)cnt;
    cntk[k] = cf;
    const float wv = 1.f / fmaxf(cf, 1.f);
    for (int s = 0; s < S_; ++s) {
      valid[k * S_ + s] = s_valid[s];
      wcol[k * S_ + s] = s_valid[s] ? wv : 0.f;
    }
    if (cnt > 1 && k >= 1) atomAddGlb(&scal[1], 1.f);
  }
}

// ---------------------------------------------------------------------------
// K3: Gram matrix G = Pm * Pm^T  (already includes 1/T since Pm scaled).
// 128x128 tiles, 8x8 per thread, fp32 VALU. grid (14,14), block 256.
// ---------------------------------------------------------------------------
__global__ __launch_bounds__(256) void k_gram(const float* __restrict__ Pm,
                                              float* __restrict__ G) {
  __shared__ float As[32][132];
  __shared__ float Bs[32][132];
  const int j0 = blockIdx.x * 128, i0 = blockIdx.y * 128;
  const int tid = threadIdx.x;
  const int tx = tid & 15, ty = tid >> 4;
  float acc[8][8];
#pragma unroll
  for (int q = 0; q < 8; ++q)
#pragma unroll
    for (int r = 0; r < 8; ++r) acc[q][r] = 0.f;
  for (int kc = 0; kc < C_; kc += 32) {
#pragma unroll
    for (int q = 0; q < 4; ++q) {
      const int lin = tid + q * 256;
      const int r = lin >> 3, kk = (lin & 7) << 2;
      const float4 va = *(const float4*)&Pm[(size_t)(i0 + r) * C_ + kc + kk];
      As[kk + 0][r] = va.x; As[kk + 1][r] = va.y;
      As[kk + 2][r] = va.z; As[kk + 3][r] = va.w;
      const float4 vb = *(const float4*)&Pm[(size_t)(j0 + r) * C_ + kc + kk];
      Bs[kk + 0][r] = vb.x; Bs[kk + 1][r] = vb.y;
      Bs[kk + 2][r] = vb.z; Bs[kk + 3][r] = vb.w;
    }
    __syncthreads();
#pragma unroll
    for (int kk = 0; kk < 32; ++kk) {
      const float4 a0 = *(const float4*)&As[kk][ty * 8];
      const float4 a1 = *(const float4*)&As[kk][ty * 8 + 4];
      const float4 b0 = *(const float4*)&Bs[kk][tx * 8];
      const float4 b1 = *(const float4*)&Bs[kk][tx * 8 + 4];
      const float av[8] = {a0.x, a0.y, a0.z, a0.w, a1.x, a1.y, a1.z, a1.w};
      const float bv[8] = {b0.x, b0.y, b0.z, b0.w, b1.x, b1.y, b1.z, b1.w};
#pragma unroll
      for (int q = 0; q < 8; ++q)
#pragma unroll
        for (int r = 0; r < 8; ++r) acc[q][r] = fmaf(av[q], bv[r], acc[q][r]);
    }
    __syncthreads();
  }
#pragma unroll
  for (int q = 0; q < 8; ++q) {
    float4 o0 = {acc[q][0], acc[q][1], acc[q][2], acc[q][3]};
    float4 o1 = {acc[q][4], acc[q][5], acc[q][6], acc[q][7]};
    float* gr = &G[(size_t)(i0 + ty * 8 + q) * GN_ + j0 + tx * 8];
    *(float4*)gr = o0;
    *(float4*)(gr + 4) = o1;
  }
}

// ---------------------------------------------------------------------------
// K4: per-anchor loss. grid (16 slots, 101 classes), block 256.
// ---------------------------------------------------------------------------
__global__ __launch_bounds__(256) void k_loss(
    const float* __restrict__ G, const int* __restrict__ valid,
    const float* __restrict__ wcol, const float* __restrict__ cntk,
    float* __restrict__ scal) {
  const int s = blockIdx.x;  // 0..15 (batch slots only = anchors)
  const int k = blockIdx.y;  // 0..100
  const int a = k * S_ + s;
  if (!valid[a]) return;  // uniform over block
  const int tid = threadIdx.x;
  const float* row = G + (size_t)a * GN_;
  float dpart = 0.f;
  for (int j = tid; j < GN_; j += 256) dpart += wcol[j] * __expf(row[j]);
  __shared__ float red[4];
#pragma unroll
  for (int o = 32; o > 0; o >>= 1) dpart += __shfl_down(dpart, o);
  if ((tid & 63) == 0) red[tid >> 6] = dpart;
  __syncthreads();
  if (tid == 0) {
    const float den = red[0] + red[1] + red[2] + red[3];
    float pos = 0.f;
    for (int n = 0; n < S_; ++n)
      if (valid[k * S_ + n]) pos += row[k * S_ + n];
    pos -= row[a];  // remove self term (diag)
    const float np = cntk[k] - 1.f;
    const float npc = fmaxf(np, 1.f);
    const float pa = -(pos - np * logf(den)) / (npc * npc);
    atomAddGlb(&scal[0], pa);
  }
}

__global__ void k_final(const float* __restrict__ scal, float* __restrict__ out) {
  out[0] = 0.1f * scal[0] / scal[1];
}

// ---------------------------------------------------------------------------
extern "C" void kernel_launch(void* const* d_in, const int* in_sizes, int n_in,
                              void* d_out, int out_size, void* d_ws, size_t ws_size,
                              hipStream_t stream) {
  const int* labels = (const int*)d_in[0];
  const float* feats = (const float*)d_in[1];
  const float* protos = (const float*)d_in[2];
  float* out = (float*)d_out;

  char* wsb = (char*)d_ws;
  size_t o = 0;
  auto nxt = [&](size_t bytes) {
    size_t r = o;
    o = (o + bytes + 255) & ~(size_t)255;
    return r;
  };
  // Small region (memset each call):
  const size_t off_sums = nxt((size_t)B_ * K_ * C_ * 4);
  const size_t off_cnts = nxt((size_t)B_ * K_ * 4);
  const size_t off_P    = nxt((size_t)GN_ * C_ * 4);
  const size_t off_val  = nxt((size_t)GN_ * 4);
  const size_t off_w    = nxt((size_t)GN_ * 4);
  const size_t off_cntk = nxt((size_t)K_ * 4);
  const size_t off_scal = nxt(8);
  const size_t small_end = o;
  // Big region: psum partials and G share storage (disjoint lifetimes).
  const size_t psum_bytes = (size_t)NPQ_ * 16 * K_ * 256 * 4;  // 26.5 MB
  const size_t g_bytes = (size_t)GN_ * GN_ * 4;                // 12.8 MB
  const size_t off_big = nxt(psum_bytes > g_bytes ? psum_bytes : g_bytes);

  float* w_sums    = (float*)(wsb + off_sums);
  unsigned* w_cnts = (unsigned*)(wsb + off_cnts);
  float* w_P       = (float*)(wsb + off_P);
  int* w_valid     = (int*)(wsb + off_val);
  float* w_w       = (float*)(wsb + off_w);
  float* w_cntk    = (float*)(wsb + off_cntk);
  float* w_scal    = (float*)(wsb + off_scal);
  float* w_psum    = (float*)(wsb + off_big);
  float* w_G       = (float*)(wsb + off_big);

  // Zero the small region (Pm pad rows feed k_gram; scalars accumulate).
  hipMemsetAsync(d_ws, 0, small_end, stream);

  k_segsum<<<1040, 256, 0, stream>>>(labels, feats, w_psum, w_cnts);
  k_reduce<<<(B_ * K_ * C_ + 255) / 256, 256, 0, stream>>>(w_psum, w_sums);
  k_protos<<<K_, 256, 0, stream>>>(w_sums, w_cnts, protos, w_P, w_valid, w_w,
                                   w_cntk, w_scal);
  k_gram<<<dim3(GN_ / 128, GN_ / 128), 256, 0, stream>>>(w_P, w_G);
  k_loss<<<dim3(B_, K_), 256, 0, stream>>>(w_G, w_valid, w_w, w_cntk, w_scal);
  k_final<<<1, 1, 0, stream>>>(w_scal, out);
}

// Round 6
// 146.366 us; speedup vs baseline: 4.9267x; 1.1372x over previous
//
#include <hip/hip_runtime.h>
#include <hip/hip_bf16.h>
#include <math.h>

// Problem constants (fixed by setup_inputs)
#define B_    16
#define C_    256
#define P_    16384          // 128*128
#define K_    101            // num_class + 1
#define S_    17             // B + 1 slots per class
#define V_    1717           // K_ * S_
#define GN_   1792           // V_ padded to 28*64
#define NPQ_  32             // pixel-slice partials (512 px per slice)
#define TEMP_ 0.07f
#define INV_SQRT_T 3.7796447300922720f   // 1/sqrt(0.07)

typedef __bf16 bf16x8 __attribute__((ext_vector_type(8)));
typedef float f32x4 __attribute__((ext_vector_type(4)));
typedef int   i32x4 __attribute__((ext_vector_type(4)));

__device__ __forceinline__ void atomAddGlb(float* p, float v) {
  __hip_atomic_fetch_add(p, v, __ATOMIC_RELAXED, __HIP_MEMORY_SCOPE_AGENT);
}

// ---------------------------------------------------------------------------
// K1: segmented sums via MFMA, zero LDS on the feature path.
// R5 ran 4 waves/SIMD (latency only partly hidden).  Now 32 pixel slices of
// 512 px -> 2048 working blocks = 8 blocks/CU = 32 waves/CU.
// Each wave owns (b, 16-ch group cg, 512-px slice pq): B-fragments stream
// straight from global (2x float4/lane), A-fragments from labels (2x int4).
// fp32 features split exactly into bf16 hi+lo, both MFMA'd into fp32 acc.
// Blocks 2048..2063: per-batch label histogram.
// ---------------------------------------------------------------------------
__global__ __launch_bounds__(256, 8) void k_segsum(
    const int* __restrict__ labels, const float* __restrict__ feats,
    float* __restrict__ psum, unsigned* __restrict__ counts) {
  __shared__ unsigned s_cnt[102];
  const int id = blockIdx.x;
  const int tid = threadIdx.x;

  if (id >= 2048) {  // ---- label counts for batch id-2048 ----
    const int b = id - 2048;
    if (tid < 102) s_cnt[tid] = 0u;
    __syncthreads();
    for (int i = 0; i < 64; ++i) {
      int lab = labels[b * P_ + i * 256 + tid];
      if ((unsigned)lab > 100u) lab = 101;
      atomicAdd(&s_cnt[lab], 1u);
    }
    __syncthreads();
    if (tid < K_) counts[b * K_ + tid] = s_cnt[tid];
    return;
  }

  // cg innermost so the 16 blocks sharing (b,pqg) labels are dispatch-adjacent
  const int cg = id & 15, pqg = (id >> 4) & 7, b = id >> 7;
  const int wv = tid >> 6, ln = tid & 63;
  const int lg = ln >> 4;    // lane group 0..3 (k-window selector)
  const int lc = ln & 15;    // lane-in-group: A row (class) / B col (channel)
  const int pq = pqg * 4 + wv;           // 0..31
  const int ch = cg * 16 + lc;
  const int pbase = pq * 512;
  const int* lrow = labels + b * P_ + pbase + lg * 8;
  const float* frow = feats + ((size_t)b * C_ + ch) * P_ + pbase + lg * 8;

  f32x4 acc[7];
#pragma unroll
  for (int t = 0; t < 7; ++t) acc[t] = (f32x4)0.f;

  for (int w = 0; w < 16; ++w) {
    const int off = w * 32;
    const i32x4 la = *(const i32x4*)&lrow[off];
    const i32x4 lb = *(const i32x4*)&lrow[off + 4];
    const float4 f0 = *(const float4*)&frow[off];
    const float4 f1 = *(const float4*)&frow[off + 4];
    // exact fp32 -> bf16 hi/lo split, packed 2 px per dword (even px = low)
    i32x4 hid, lod;
    {
      const float fx[8] = {f0.x, f0.y, f0.z, f0.w, f1.x, f1.y, f1.z, f1.w};
#pragma unroll
      for (int p2 = 0; p2 < 4; ++p2) {
        const unsigned u0 = __float_as_uint(fx[2 * p2]);
        const unsigned u1 = __float_as_uint(fx[2 * p2 + 1]);
        hid[p2] = (int)((u0 >> 16) | (u1 & 0xFFFF0000u));
        const float h0 = __uint_as_float(u0 & 0xFFFF0000u);
        const float h1 = __uint_as_float(u1 & 0xFFFF0000u);
        const unsigned v0 = __float_as_uint(fx[2 * p2] - h0);
        const unsigned v1 = __float_as_uint(fx[2 * p2 + 1] - h1);
        lod[p2] = (int)((v0 >> 16) | (v1 & 0xFFFF0000u));
      }
    }
    const bf16x8 bh = __builtin_bit_cast(bf16x8, hid);
    const bf16x8 bl = __builtin_bit_cast(bf16x8, lod);
    int d[8];
    d[0] = la.x - lc; d[1] = la.y - lc; d[2] = la.z - lc; d[3] = la.w - lc;
    d[4] = lb.x - lc; d[5] = lb.y - lc; d[6] = lb.z - lc; d[7] = lb.w - lc;
#pragma unroll
    for (int t = 0; t < 7; ++t) {
      const int m0 = t * 16;
      i32x4 av;
#pragma unroll
      for (int r = 0; r < 4; ++r) {
        unsigned v = (d[2 * r] == m0) ? 0x3F80u : 0u;
        if (d[2 * r + 1] == m0) v |= 0x3F800000u;
        av[r] = (int)v;
      }
      const bf16x8 af = __builtin_bit_cast(bf16x8, av);
      acc[t] = __builtin_amdgcn_mfma_f32_16x16x32_bf16(af, bh, acc[t], 0, 0, 0);
      acc[t] = __builtin_amdgcn_mfma_f32_16x16x32_bf16(af, bl, acc[t], 0, 0, 0);
    }
  }
  // epilogue: D row = t*16 + lg*4 + r (class), col = lc (channel)
  float* pout = psum + (((size_t)pq * 16 + b) * K_) * 256 + cg * 16 + lc;
#pragma unroll
  for (int t = 0; t < 7; ++t)
#pragma unroll
    for (int r = 0; r < 4; ++r) {
      const int row = t * 16 + lg * 4 + r;
      if (row < K_) pout[(size_t)row * 256] = acc[t][r];
    }
}

// ---------------------------------------------------------------------------
// K1b: reduce the 32 pixel-slice partials -> sums[b][k][c]. float4 per thread.
// ---------------------------------------------------------------------------
__global__ __launch_bounds__(256) void k_reduce(const float* __restrict__ psum,
                                                float* __restrict__ sums) {
  const int id = blockIdx.x * 256 + threadIdx.x;
  if (id >= B_ * K_ * 64) return;
  const int c4 = (id & 63) * 4;
  const int rem = id >> 6;
  const int k = rem % K_;
  const int b = rem / K_;
  float4 s = {0.f, 0.f, 0.f, 0.f};
#pragma unroll
  for (int pq = 0; pq < NPQ_; ++pq) {
    const float4 v = *(const float4*)&psum[(((size_t)pq * 16 + b) * K_ + k) * 256 + c4];
    s.x += v.x; s.y += v.y; s.z += v.z; s.w += v.w;
  }
  *(float4*)&sums[((size_t)b * K_ + k) * C_ + c4] = s;
}

// ---------------------------------------------------------------------------
// K2: normalized prototype slots scaled by 1/sqrt(T), emitted as exact bf16
// hi/lo planes (for the MFMA gram); valid mask, per-class cnt, column weight,
// cnt_exist. grid K_ blocks, 256 threads.
// ---------------------------------------------------------------------------
__global__ __launch_bounds__(256) void k_protos(
    const float* __restrict__ sums, const unsigned* __restrict__ counts,
    const float* __restrict__ prototypes, unsigned short* __restrict__ PmH,
    unsigned short* __restrict__ PmL, int* __restrict__ valid,
    float* __restrict__ wcol, float* __restrict__ cntk,
    float* __restrict__ scal) {
  const int k = blockIdx.x;
  const int c = threadIdx.x;  // 0..255 = channel
  __shared__ float red[4];
  __shared__ int s_valid[S_];
  for (int s = 0; s < S_; ++s) {
    float val;
    int pres;
    if (s < B_) {
      const unsigned cb = counts[s * K_ + k];
      val = sums[((size_t)s * K_ + k) * C_ + c] / fmaxf((float)cb, 1.f);
      pres = (cb > 0u) && (k >= 1);
    } else {
      val = prototypes[k * C_ + c];
      pres = (k >= 1);
    }
    float ss = val * val;
#pragma unroll
    for (int o = 32; o > 0; o >>= 1) ss += __shfl_down(ss, o);
    if ((c & 63) == 0) red[c >> 6] = ss;
    __syncthreads();
    const float tot = red[0] + red[1] + red[2] + red[3];
    const float nrm = fmaxf(sqrtf(tot), 1e-12f);
    const float pv = pres ? (val / nrm) * INV_SQRT_T : 0.f;
    const unsigned u = __float_as_uint(pv);
    const float lo = pv - __uint_as_float(u & 0xFFFF0000u);
    const size_t idx = ((size_t)k * S_ + s) * C_ + c;
    PmH[idx] = (unsigned short)(u >> 16);
    PmL[idx] = (unsigned short)(__float_as_uint(lo) >> 16);
    if (c == 0) s_valid[s] = pres;
    __syncthreads();
  }
  if (c == 0) {
    int cnt = 0;
    for (int s = 0; s < S_; ++s) cnt += s_valid[s];
    const float cf = (float)cnt;
    cntk[k] = cf;
    const float wv = 1.f / fmaxf(cf, 1.f);
    for (int s = 0; s < S_; ++s) {
      valid[k * S_ + s] = s_valid[s];
      wcol[k * S_ + s] = s_valid[s] ? wv : 0.f;
    }
    if (cnt > 1 && k >= 1) atomAddGlb(&scal[1], 1.f);
  }
}

// ---------------------------------------------------------------------------
// K3: Gram G = Pm*Pm^T via bf16 MFMA with exact hi/lo split:
// G ~= H*H^T + H*L^T + L*H^T   (lo*lo ~ 2^-16 relative, dropped).
// A/B k-slot convention (k = (lane>>4)*8 + j on BOTH operands) is the one
// verified absmax-0.0 by k_segsum.  64x64 tile per wave, 4 waves/block,
// grid 196 blocks = 784 tiles; operands L2-resident (1.8 MB).
// ---------------------------------------------------------------------------
__global__ __launch_bounds__(256) void k_gram(
    const unsigned short* __restrict__ PmH,
    const unsigned short* __restrict__ PmL, float* __restrict__ G) {
  const int tid = threadIdx.x;
  const int wv = tid >> 6, ln = tid & 63;
  const int gid = blockIdx.x * 4 + wv;       // 0..783
  const int ri = gid / 28, cj = gid % 28;    // 64x64 tile coords
  const int lg = ln >> 4, lc = ln & 15;

  f32x4 acc[4][4];
#pragma unroll
  for (int m = 0; m < 4; ++m)
#pragma unroll
    for (int n = 0; n < 4; ++n) acc[m][n] = (f32x4)0.f;

#pragma unroll
  for (int ks = 0; ks < 8; ++ks) {
    const int kb = ks * 32 + lg * 8;
    bf16x8 aH[4], aL[4], bH[4], bL[4];
#pragma unroll
    for (int m = 0; m < 4; ++m) {
      const size_t ra = (size_t)(ri * 64 + m * 16 + lc) * C_ + kb;
      aH[m] = __builtin_bit_cast(bf16x8, *(const i32x4*)&PmH[ra]);
      aL[m] = __builtin_bit_cast(bf16x8, *(const i32x4*)&PmL[ra]);
      const size_t rb = (size_t)(cj * 64 + m * 16 + lc) * C_ + kb;
      bH[m] = __builtin_bit_cast(bf16x8, *(const i32x4*)&PmH[rb]);
      bL[m] = __builtin_bit_cast(bf16x8, *(const i32x4*)&PmL[rb]);
    }
#pragma unroll
    for (int m = 0; m < 4; ++m)
#pragma unroll
      for (int n = 0; n < 4; ++n) {
        acc[m][n] = __builtin_amdgcn_mfma_f32_16x16x32_bf16(aH[m], bH[n], acc[m][n], 0, 0, 0);
        acc[m][n] = __builtin_amdgcn_mfma_f32_16x16x32_bf16(aH[m], bL[n], acc[m][n], 0, 0, 0);
        acc[m][n] = __builtin_amdgcn_mfma_f32_16x16x32_bf16(aL[m], bH[n], acc[m][n], 0, 0, 0);
      }
  }
  // D: row = m*16 + lg*4 + r, col = n*16 + lc
#pragma unroll
  for (int m = 0; m < 4; ++m)
#pragma unroll
    for (int r = 0; r < 4; ++r) {
      float* gr = &G[(size_t)(ri * 64 + m * 16 + lg * 4 + r) * GN_ + cj * 64 + lc];
#pragma unroll
      for (int n = 0; n < 4; ++n) gr[n * 16] = acc[m][n][r];
    }
}

// ---------------------------------------------------------------------------
// K4: per-anchor loss. grid (16 slots, 101 classes), block 256.
// ---------------------------------------------------------------------------
__global__ __launch_bounds__(256) void k_loss(
    const float* __restrict__ G, const int* __restrict__ valid,
    const float* __restrict__ wcol, const float* __restrict__ cntk,
    float* __restrict__ scal) {
  const int s = blockIdx.x;  // 0..15 (batch slots only = anchors)
  const int k = blockIdx.y;  // 0..100
  const int a = k * S_ + s;
  if (!valid[a]) return;  // uniform over block
  const int tid = threadIdx.x;
  const float* row = G + (size_t)a * GN_;
  float dpart = 0.f;
  for (int j = tid; j < GN_; j += 256) dpart += wcol[j] * __expf(row[j]);
  __shared__ float red[4];
#pragma unroll
  for (int o = 32; o > 0; o >>= 1) dpart += __shfl_down(dpart, o);
  if ((tid & 63) == 0) red[tid >> 6] = dpart;
  __syncthreads();
  if (tid == 0) {
    const float den = red[0] + red[1] + red[2] + red[3];
    float pos = 0.f;
    for (int n = 0; n < S_; ++n)
      if (valid[k * S_ + n]) pos += row[k * S_ + n];
    pos -= row[a];  // remove self term (diag)
    const float np = cntk[k] - 1.f;
    const float npc = fmaxf(np, 1.f);
    const float pa = -(pos - np * logf(den)) / (npc * npc);
    atomAddGlb(&scal[0], pa);
  }
}

__global__ void k_final(const float* __restrict__ scal, float* __restrict__ out) {
  out[0] = 0.1f * scal[0] / scal[1];
}

// ---------------------------------------------------------------------------
extern "C" void kernel_launch(void* const* d_in, const int* in_sizes, int n_in,
                              void* d_out, int out_size, void* d_ws, size_t ws_size,
                              hipStream_t stream) {
  const int* labels = (const int*)d_in[0];
  const float* feats = (const float*)d_in[1];
  const float* protos = (const float*)d_in[2];
  float* out = (float*)d_out;

  char* wsb = (char*)d_ws;
  size_t o = 0;
  auto nxt = [&](size_t bytes) {
    size_t r = o;
    o = (o + bytes + 255) & ~(size_t)255;
    return r;
  };
  // Small region (memset each call):
  const size_t off_sums = nxt((size_t)B_ * K_ * C_ * 4);
  const size_t off_cnts = nxt((size_t)B_ * K_ * 4);
  const size_t off_PH   = nxt((size_t)GN_ * C_ * 2);
  const size_t off_PL   = nxt((size_t)GN_ * C_ * 2);
  const size_t off_val  = nxt((size_t)GN_ * 4);
  const size_t off_w    = nxt((size_t)GN_ * 4);
  const size_t off_cntk = nxt((size_t)K_ * 4);
  const size_t off_scal = nxt(8);
  const size_t small_end = o;
  // Big region: psum partials and G share storage (disjoint lifetimes).
  const size_t psum_bytes = (size_t)NPQ_ * 16 * K_ * 256 * 4;  // 52.9 MB
  const size_t g_bytes = (size_t)GN_ * GN_ * 4;                // 12.8 MB
  const size_t off_big = nxt(psum_bytes > g_bytes ? psum_bytes : g_bytes);

  float* w_sums    = (float*)(wsb + off_sums);
  unsigned* w_cnts = (unsigned*)(wsb + off_cnts);
  unsigned short* w_PH = (unsigned short*)(wsb + off_PH);
  unsigned short* w_PL = (unsigned short*)(wsb + off_PL);
  int* w_valid     = (int*)(wsb + off_val);
  float* w_w       = (float*)(wsb + off_w);
  float* w_cntk    = (float*)(wsb + off_cntk);
  float* w_scal    = (float*)(wsb + off_scal);
  float* w_psum    = (float*)(wsb + off_big);
  float* w_G       = (float*)(wsb + off_big);

  // Zero the small region (PmH/PmL pad rows feed k_gram; scalars accumulate).
  hipMemsetAsync(d_ws, 0, small_end, stream);

  k_segsum<<<2064, 256, 0, stream>>>(labels, feats, w_psum, w_cnts);
  k_reduce<<<(B_ * K_ * 64 + 255) / 256, 256, 0, stream>>>(w_psum, w_sums);
  k_protos<<<K_, 256, 0, stream>>>(w_sums, w_cnts, protos, w_PH, w_PL, w_valid,
                                   w_w, w_cntk, w_scal);
  k_gram<<<196, 256, 0, stream>>>(w_PH, w_PL, w_G);
  k_loss<<<dim3(B_, K_), 256, 0, stream>>>(w_G, w_valid, w_w, w_cntk, w_scal);
  k_final<<<1, 1, 0, stream>>>(w_scal, out);
}

// Round 7
// 134.506 us; speedup vs baseline: 5.3611x; 1.0882x over previous
//
#include <hip/hip_runtime.h>
#include <hip/hip_bf16.h>
#include <math.h>

// Problem constants (fixed by setup_inputs)
#define B_    16
#define C_    256
#define P_    16384          // 128*128
#define K_    101            // num_class + 1
#define S_    17             // B + 1 slots per class
#define V_    1717           // K_ * S_
#define GN_   1792           // V_ padded to 28*64
#define NPQ_  8              // pixel-slice partials (2048 px per slice, block-reduced)
#define TEMP_ 0.07f
#define INV_SQRT_T 3.7796447300922720f   // 1/sqrt(0.07)

typedef __bf16 bf16x8 __attribute__((ext_vector_type(8)));
typedef float f32x4 __attribute__((ext_vector_type(4)));
typedef int   i32x4 __attribute__((ext_vector_type(4)));

__device__ __forceinline__ void atomAddGlb(float* p, float v) {
  __hip_atomic_fetch_add(p, v, __ATOMIC_RELAXED, __HIP_MEMORY_SCOPE_AGENT);
}

// ---------------------------------------------------------------------------
// K1: segmented sums via MFMA, zero LDS on the feature path.
// 2048 working blocks (8/CU = 32 waves/CU), each block = (b, 16-ch group cg,
// 2048-px slice pqg); its 4 waves take 512-px sub-slices, then the block
// reduces the 4 accumulators through 4KB LDS (plain adds) and wave 0 writes
// ONE psum slab -> psum shrinks 53->13.2 MB vs R6 (cuts ~80MB HBM round-trip).
// B-fragments stream from global (2x float4/lane), A from labels (2x int4),
// fp32 split exactly into bf16 hi+lo, both MFMA'd into fp32 acc.
// Blocks 2048..2063: per-batch label histogram.
// ---------------------------------------------------------------------------
__global__ __launch_bounds__(256, 8) void k_segsum(
    const int* __restrict__ labels, const float* __restrict__ feats,
    float* __restrict__ psum, unsigned* __restrict__ counts) {
  __shared__ unsigned s_cnt[102];
  __shared__ float4 s_red[256];
  const int id = blockIdx.x;
  const int tid = threadIdx.x;

  if (id >= 2048) {  // ---- label counts for batch id-2048 ----
    const int b = id - 2048;
    if (tid < 102) s_cnt[tid] = 0u;
    __syncthreads();
    for (int i = 0; i < 64; ++i) {
      int lab = labels[b * P_ + i * 256 + tid];
      if ((unsigned)lab > 100u) lab = 101;
      atomicAdd(&s_cnt[lab], 1u);
    }
    __syncthreads();
    if (tid < K_) counts[b * K_ + tid] = s_cnt[tid];
    return;
  }

  // cg innermost so the 16 blocks sharing (b,pqg) labels are dispatch-adjacent
  const int cg = id & 15, pqg = (id >> 4) & 7, b = id >> 7;
  const int wv = tid >> 6, ln = tid & 63;
  const int lg = ln >> 4;    // lane group 0..3 (k-window selector)
  const int lc = ln & 15;    // lane-in-group: A row (class) / B col (channel)
  const int pq = pqg * 4 + wv;           // 0..31
  const int ch = cg * 16 + lc;
  const int pbase = pq * 512;
  const int* lrow = labels + b * P_ + pbase + lg * 8;
  const float* frow = feats + ((size_t)b * C_ + ch) * P_ + pbase + lg * 8;

  f32x4 acc[7];
#pragma unroll
  for (int t = 0; t < 7; ++t) acc[t] = (f32x4)0.f;

  for (int w = 0; w < 16; ++w) {
    const int off = w * 32;
    const i32x4 la = *(const i32x4*)&lrow[off];
    const i32x4 lb = *(const i32x4*)&lrow[off + 4];
    const float4 f0 = *(const float4*)&frow[off];
    const float4 f1 = *(const float4*)&frow[off + 4];
    // exact fp32 -> bf16 hi/lo split, packed 2 px per dword (even px = low)
    i32x4 hid, lod;
    {
      const float fx[8] = {f0.x, f0.y, f0.z, f0.w, f1.x, f1.y, f1.z, f1.w};
#pragma unroll
      for (int p2 = 0; p2 < 4; ++p2) {
        const unsigned u0 = __float_as_uint(fx[2 * p2]);
        const unsigned u1 = __float_as_uint(fx[2 * p2 + 1]);
        hid[p2] = (int)((u0 >> 16) | (u1 & 0xFFFF0000u));
        const float h0 = __uint_as_float(u0 & 0xFFFF0000u);
        const float h1 = __uint_as_float(u1 & 0xFFFF0000u);
        const unsigned v0 = __float_as_uint(fx[2 * p2] - h0);
        const unsigned v1 = __float_as_uint(fx[2 * p2 + 1] - h1);
        lod[p2] = (int)((v0 >> 16) | (v1 & 0xFFFF0000u));
      }
    }
    const bf16x8 bh = __builtin_bit_cast(bf16x8, hid);
    const bf16x8 bl = __builtin_bit_cast(bf16x8, lod);
    int d[8];
    d[0] = la.x - lc; d[1] = la.y - lc; d[2] = la.z - lc; d[3] = la.w - lc;
    d[4] = lb.x - lc; d[5] = lb.y - lc; d[6] = lb.z - lc; d[7] = lb.w - lc;
#pragma unroll
    for (int t = 0; t < 7; ++t) {
      const int m0 = t * 16;
      i32x4 av;
#pragma unroll
      for (int r = 0; r < 4; ++r) {
        unsigned v = (d[2 * r] == m0) ? 0x3F80u : 0u;
        if (d[2 * r + 1] == m0) v |= 0x3F800000u;
        av[r] = (int)v;
      }
      const bf16x8 af = __builtin_bit_cast(bf16x8, av);
      acc[t] = __builtin_amdgcn_mfma_f32_16x16x32_bf16(af, bh, acc[t], 0, 0, 0);
      acc[t] = __builtin_amdgcn_mfma_f32_16x16x32_bf16(af, bl, acc[t], 0, 0, 0);
    }
  }
  // ---- block-level reduction over the 4 waves, wave 0 writes one slab ----
  float* pout = psum + (((size_t)pqg * 16 + b) * K_) * 256 + cg * 16 + lc;
#pragma unroll
  for (int t = 0; t < 7; ++t) {
    s_red[wv * 64 + ln] = (float4){acc[t][0], acc[t][1], acc[t][2], acc[t][3]};
    __syncthreads();
    if (wv == 0) {
      const float4 a0 = s_red[ln], a1 = s_red[64 + ln];
      const float4 a2 = s_red[128 + ln], a3 = s_red[192 + ln];
      const float sr[4] = {a0.x + a1.x + a2.x + a3.x, a0.y + a1.y + a2.y + a3.y,
                           a0.z + a1.z + a2.z + a3.z, a0.w + a1.w + a2.w + a3.w};
#pragma unroll
      for (int r = 0; r < 4; ++r) {
        const int row = t * 16 + lg * 4 + r;
        if (row < K_) pout[(size_t)row * 256] = sr[r];
      }
    }
    __syncthreads();
  }
}

// ---------------------------------------------------------------------------
// K1b: reduce the 8 pixel-slice partials -> sums[b][k][c]. float4 per thread.
// ---------------------------------------------------------------------------
__global__ __launch_bounds__(256) void k_reduce(const float* __restrict__ psum,
                                                float* __restrict__ sums) {
  const int id = blockIdx.x * 256 + threadIdx.x;
  if (id >= B_ * K_ * 64) return;
  const int c4 = (id & 63) * 4;
  const int rem = id >> 6;
  const int k = rem % K_;
  const int b = rem / K_;
  float4 s = {0.f, 0.f, 0.f, 0.f};
#pragma unroll
  for (int pq = 0; pq < NPQ_; ++pq) {
    const float4 v = *(const float4*)&psum[(((size_t)pq * 16 + b) * K_ + k) * 256 + c4];
    s.x += v.x; s.y += v.y; s.z += v.z; s.w += v.w;
  }
  *(float4*)&sums[((size_t)b * K_ + k) * C_ + c4] = s;
}

// ---------------------------------------------------------------------------
// K2: normalized prototype slots scaled by 1/sqrt(T), emitted as exact bf16
// hi/lo planes (for the MFMA gram); valid mask, per-class cnt, column weight,
// cnt_exist. grid K_ blocks, 256 threads.
// ---------------------------------------------------------------------------
__global__ __launch_bounds__(256) void k_protos(
    const float* __restrict__ sums, const unsigned* __restrict__ counts,
    const float* __restrict__ prototypes, unsigned short* __restrict__ PmH,
    unsigned short* __restrict__ PmL, int* __restrict__ valid,
    float* __restrict__ wcol, float* __restrict__ cntk,
    float* __restrict__ scal) {
  const int k = blockIdx.x;
  const int c = threadIdx.x;  // 0..255 = channel
  __shared__ float red[4];
  __shared__ int s_valid[S_];
  for (int s = 0; s < S_; ++s) {
    float val;
    int pres;
    if (s < B_) {
      const unsigned cb = counts[s * K_ + k];
      val = sums[((size_t)s * K_ + k) * C_ + c] / fmaxf((float)cb, 1.f);
      pres = (cb > 0u) && (k >= 1);
    } else {
      val = prototypes[k * C_ + c];
      pres = (k >= 1);
    }
    float ss = val * val;
#pragma unroll
    for (int o = 32; o > 0; o >>= 1) ss += __shfl_down(ss, o);
    if ((c & 63) == 0) red[c >> 6] = ss;
    __syncthreads();
    const float tot = red[0] + red[1] + red[2] + red[3];
    const float nrm = fmaxf(sqrtf(tot), 1e-12f);
    const float pv = pres ? (val / nrm) * INV_SQRT_T : 0.f;
    const unsigned u = __float_as_uint(pv);
    const float lo = pv - __uint_as_float(u & 0xFFFF0000u);
    const size_t idx = ((size_t)k * S_ + s) * C_ + c;
    PmH[idx] = (unsigned short)(u >> 16);
    PmL[idx] = (unsigned short)(__float_as_uint(lo) >> 16);
    if (c == 0) s_valid[s] = pres;
    __syncthreads();
  }
  if (c == 0) {
    int cnt = 0;
    for (int s = 0; s < S_; ++s) cnt += s_valid[s];
    const float cf = (float)cnt;
    cntk[k] = cf;
    const float wv = 1.f / fmaxf(cf, 1.f);
    for (int s = 0; s < S_; ++s) {
      valid[k * S_ + s] = s_valid[s];
      wcol[k * S_ + s] = s_valid[s] ? wv : 0.f;
    }
    if (cnt > 1 && k >= 1) atomAddGlb(&scal[1], 1.f);
  }
}

// ---------------------------------------------------------------------------
// K3: Gram G = Pm*Pm^T via bf16 MFMA with exact hi/lo split:
// G ~= H*H^T + H*L^T + L*H^T   (lo*lo ~ 2^-16 relative, dropped).
// 64x64 tile per wave, 4 waves/block, grid 196 blocks = 784 tiles.
// ---------------------------------------------------------------------------
__global__ __launch_bounds__(256) void k_gram(
    const unsigned short* __restrict__ PmH,
    const unsigned short* __restrict__ PmL, float* __restrict__ G) {
  const int tid = threadIdx.x;
  const int wv = tid >> 6, ln = tid & 63;
  const int gid = blockIdx.x * 4 + wv;       // 0..783
  const int ri = gid / 28, cj = gid % 28;    // 64x64 tile coords
  const int lg = ln >> 4, lc = ln & 15;

  f32x4 acc[4][4];
#pragma unroll
  for (int m = 0; m < 4; ++m)
#pragma unroll
    for (int n = 0; n < 4; ++n) acc[m][n] = (f32x4)0.f;

#pragma unroll
  for (int ks = 0; ks < 8; ++ks) {
    const int kb = ks * 32 + lg * 8;
    bf16x8 aH[4], aL[4], bH[4], bL[4];
#pragma unroll
    for (int m = 0; m < 4; ++m) {
      const size_t ra = (size_t)(ri * 64 + m * 16 + lc) * C_ + kb;
      aH[m] = __builtin_bit_cast(bf16x8, *(const i32x4*)&PmH[ra]);
      aL[m] = __builtin_bit_cast(bf16x8, *(const i32x4*)&PmL[ra]);
      const size_t rb = (size_t)(cj * 64 + m * 16 + lc) * C_ + kb;
      bH[m] = __builtin_bit_cast(bf16x8, *(const i32x4*)&PmH[rb]);
      bL[m] = __builtin_bit_cast(bf16x8, *(const i32x4*)&PmL[rb]);
    }
#pragma unroll
    for (int m = 0; m < 4; ++m)
#pragma unroll
      for (int n = 0; n < 4; ++n) {
        acc[m][n] = __builtin_amdgcn_mfma_f32_16x16x32_bf16(aH[m], bH[n], acc[m][n], 0, 0, 0);
        acc[m][n] = __builtin_amdgcn_mfma_f32_16x16x32_bf16(aH[m], bL[n], acc[m][n], 0, 0, 0);
        acc[m][n] = __builtin_amdgcn_mfma_f32_16x16x32_bf16(aL[m], bH[n], acc[m][n], 0, 0, 0);
      }
  }
  // D: row = m*16 + lg*4 + r, col = n*16 + lc
#pragma unroll
  for (int m = 0; m < 4; ++m)
#pragma unroll
    for (int r = 0; r < 4; ++r) {
      float* gr = &G[(size_t)(ri * 64 + m * 16 + lg * 4 + r) * GN_ + cj * 64 + lc];
#pragma unroll
      for (int n = 0; n < 4; ++n) gr[n * 16] = acc[m][n][r];
    }
}

// ---------------------------------------------------------------------------
// K4: per-anchor loss. grid (16 slots, 101 classes), block 256.
// ---------------------------------------------------------------------------
__global__ __launch_bounds__(256) void k_loss(
    const float* __restrict__ G, const int* __restrict__ valid,
    const float* __restrict__ wcol, const float* __restrict__ cntk,
    float* __restrict__ scal) {
  const int s = blockIdx.x;  // 0..15 (batch slots only = anchors)
  const int k = blockIdx.y;  // 0..100
  const int a = k * S_ + s;
  if (!valid[a]) return;  // uniform over block
  const int tid = threadIdx.x;
  const float* row = G + (size_t)a * GN_;
  float dpart = 0.f;
  for (int j = tid; j < GN_; j += 256) dpart += wcol[j] * __expf(row[j]);
  __shared__ float red[4];
#pragma unroll
  for (int o = 32; o > 0; o >>= 1) dpart += __shfl_down(dpart, o);
  if ((tid & 63) == 0) red[tid >> 6] = dpart;
  __syncthreads();
  if (tid == 0) {
    const float den = red[0] + red[1] + red[2] + red[3];
    float pos = 0.f;
    for (int n = 0; n < S_; ++n)
      if (valid[k * S_ + n]) pos += row[k * S_ + n];
    pos -= row[a];  // remove self term (diag)
    const float np = cntk[k] - 1.f;
    const float npc = fmaxf(np, 1.f);
    const float pa = -(pos - np * logf(den)) / (npc * npc);
    atomAddGlb(&scal[0], pa);
  }
}

__global__ void k_final(const float* __restrict__ scal, float* __restrict__ out) {
  out[0] = 0.1f * scal[0] / scal[1];
}

// ---------------------------------------------------------------------------
extern "C" void kernel_launch(void* const* d_in, const int* in_sizes, int n_in,
                              void* d_out, int out_size, void* d_ws, size_t ws_size,
                              hipStream_t stream) {
  const int* labels = (const int*)d_in[0];
  const float* feats = (const float*)d_in[1];
  const float* protos = (const float*)d_in[2];
  float* out = (float*)d_out;

  char* wsb = (char*)d_ws;
  size_t o = 0;
  auto nxt = [&](size_t bytes) {
    size_t r = o;
    o = (o + bytes + 255) & ~(size_t)255;
    return r;
  };
  // Small region (memset each call):
  const size_t off_sums = nxt((size_t)B_ * K_ * C_ * 4);
  const size_t off_cnts = nxt((size_t)B_ * K_ * 4);
  const size_t off_PH   = nxt((size_t)GN_ * C_ * 2);
  const size_t off_PL   = nxt((size_t)GN_ * C_ * 2);
  const size_t off_val  = nxt((size_t)GN_ * 4);
  const size_t off_w    = nxt((size_t)GN_ * 4);
  const size_t off_cntk = nxt((size_t)K_ * 4);
  const size_t off_scal = nxt(8);
  const size_t small_end = o;
  // Big region: psum partials and G share storage (disjoint lifetimes).
  const size_t psum_bytes = (size_t)NPQ_ * 16 * K_ * 256 * 4;  // 13.2 MB
  const size_t g_bytes = (size_t)GN_ * GN_ * 4;                // 12.8 MB
  const size_t off_big = nxt(psum_bytes > g_bytes ? psum_bytes : g_bytes);

  float* w_sums    = (float*)(wsb + off_sums);
  unsigned* w_cnts = (unsigned*)(wsb + off_cnts);
  unsigned short* w_PH = (unsigned short*)(wsb + off_PH);
  unsigned short* w_PL = (unsigned short*)(wsb + off_PL);
  int* w_valid     = (int*)(wsb + off_val);
  float* w_w       = (float*)(wsb + off_w);
  float* w_cntk    = (float*)(wsb + off_cntk);
  float* w_scal    = (float*)(wsb + off_scal);
  float* w_psum    = (float*)(wsb + off_big);
  float* w_G       = (float*)(wsb + off_big);

  // Zero the small region (PmH/PmL pad rows feed k_gram; scalars accumulate).
  hipMemsetAsync(d_ws, 0, small_end, stream);

  k_segsum<<<2064, 256, 0, stream>>>(labels, feats, w_psum, w_cnts);
  k_reduce<<<(B_ * K_ * 64 + 255) / 256, 256, 0, stream>>>(w_psum, w_sums);
  k_protos<<<K_, 256, 0, stream>>>(w_sums, w_cnts, protos, w_PH, w_PL, w_valid,
                                   w_w, w_cntk, w_scal);
  k_gram<<<196, 256, 0, stream>>>(w_PH, w_PL, w_G);
  k_loss<<<dim3(B_, K_), 256, 0, stream>>>(w_G, w_valid, w_w, w_cntk, w_scal);
  k_final<<<1, 1, 0, stream>>>(w_scal, out);
}

// Round 8
// 128.779 us; speedup vs baseline: 5.5995x; 1.0445x over previous
//
#include <hip/hip_runtime.h>
#include <hip/hip_bf16.h>
#include <math.h>

// Problem constants (fixed by setup_inputs)
#define B_    16
#define C_    256
#define P_    16384          // 128*128
#define K_    101            // num_class + 1
#define S_    17             // B + 1 slots per class
#define V_    1717           // K_ * S_
#define GN_   1792           // V_ padded to 28*64
#define NPQ_  8              // pixel-slice partials (2048 px per slice)
#define TEMP_ 0.07f
#define INV_SQRT_T 3.7796447300922720f   // 1/sqrt(0.07)

typedef __bf16 bf16x8 __attribute__((ext_vector_type(8)));
typedef float f32x4 __attribute__((ext_vector_type(4)));
typedef int   i32x4 __attribute__((ext_vector_type(4)));

__device__ __forceinline__ void atomAddGlb(float* p, float v) {
  __hip_atomic_fetch_add(p, v, __ATOMIC_RELAXED, __HIP_MEMORY_SCOPE_AGENT);
}

// pack fp32 x into one dword: low16 = bf16(hi), high16 = bf16(x - hi). Exact.
__device__ __forceinline__ unsigned packHiLo(float x) {
  const unsigned u = __float_as_uint(x);
  const unsigned h = u & 0xFFFF0000u;
  const unsigned l = __float_as_uint(x - __uint_as_float(h));
  // dst bytes: [l3,l2,u3,u2] -> v_perm_b32(l, u, 0x07060302)
  return __builtin_amdgcn_perm(l, u, 0x07060302u);
}

// ---------------------------------------------------------------------------
// K1: segmented sums via MFMA with interleaved hi|lo k-packing.
// Pixel p -> k-slots (2p,2p+1) = (hi,lo); A-matrix duplicates onehot across
// the pair (0x3F803F80), so A-build = cmp+cndmask per reg, and each MFMA
// covers 16 px exactly.  Each wave owns 32 channels (two 16-ch tiles sharing
// the SAME A-fragments -> label-side VALU amortized 2x) and a 512-px slice.
// Grid: 1024 working blocks (b 16 x pqg 8 x cg 8) @ (256,4) = 16 waves/CU;
// blocks 1024..1039: per-batch label histogram.
// Block epilogue: 4-wave LDS reduce, waves 0/1 write one psum slab (13.2 MB).
// ---------------------------------------------------------------------------
__global__ __launch_bounds__(256, 4) void k_segsum(
    const int* __restrict__ labels, const float* __restrict__ feats,
    float* __restrict__ psum, unsigned* __restrict__ counts) {
  __shared__ unsigned s_cnt[102];
  __shared__ f32x4 s_red[2][256];
  const int id = blockIdx.x;
  const int tid = threadIdx.x;

  if (id >= 1024) {  // ---- label counts for batch id-1024 ----
    const int b = id - 1024;
    if (tid < 102) s_cnt[tid] = 0u;
    __syncthreads();
    for (int i = 0; i < 64; ++i) {
      int lab = labels[b * P_ + i * 256 + tid];
      if ((unsigned)lab > 100u) lab = 101;
      atomicAdd(&s_cnt[lab], 1u);
    }
    __syncthreads();
    if (tid < K_) counts[b * K_ + tid] = s_cnt[tid];
    return;
  }

  // cg innermost so the 8 blocks sharing (b,pqg) labels are dispatch-adjacent
  const int cg = id & 7, pqg = (id >> 3) & 7, b = id >> 6;
  const int wv = tid >> 6, ln = tid & 63;
  const int lg = ln >> 4;    // lane group 0..3
  const int lc = ln & 15;    // A row (class) / B col (channel)
  const int pbase = pqg * 2048 + wv * 512;
  const int* lptr = labels + b * P_ + pbase + lg * 4;
  const float* fbase =
      feats + ((size_t)b * C_ + cg * 32 + lc) * P_ + pbase + lg * 4;

  f32x4 acc[2][7];
#pragma unroll
  for (int ct = 0; ct < 2; ++ct)
#pragma unroll
    for (int t = 0; t < 7; ++t) acc[ct][t] = (f32x4)0.f;

  for (int w = 0; w < 16; ++w) {
    const int off = w * 32;
    // labels for window0 (px lg*4..+3) and window1 (px 16+lg*4..+3)
    const i32x4 la0 = *(const i32x4*)&lptr[off];
    const i32x4 la1 = *(const i32x4*)&lptr[off + 16];
    int d0[4], d1[4];
#pragma unroll
    for (int r = 0; r < 4; ++r) { d0[r] = la0[r] - lc; d1[r] = la1[r] - lc; }
    // features: both chtiles, both windows; pack hi|lo per pixel
    i32x4 p0[2], p1[2];
#pragma unroll
    for (int ct = 0; ct < 2; ++ct) {
      const float4 f0 = *(const float4*)&fbase[(size_t)ct * 16 * P_ + off];
      const float4 f1 = *(const float4*)&fbase[(size_t)ct * 16 * P_ + off + 16];
      p0[ct][0] = (int)packHiLo(f0.x); p0[ct][1] = (int)packHiLo(f0.y);
      p0[ct][2] = (int)packHiLo(f0.z); p0[ct][3] = (int)packHiLo(f0.w);
      p1[ct][0] = (int)packHiLo(f1.x); p1[ct][1] = (int)packHiLo(f1.y);
      p1[ct][2] = (int)packHiLo(f1.z); p1[ct][3] = (int)packHiLo(f1.w);
    }
    const bf16x8 b00 = __builtin_bit_cast(bf16x8, p0[0]);
    const bf16x8 b10 = __builtin_bit_cast(bf16x8, p1[0]);
    const bf16x8 b01 = __builtin_bit_cast(bf16x8, p0[1]);
    const bf16x8 b11 = __builtin_bit_cast(bf16x8, p1[1]);
#pragma unroll
    for (int t = 0; t < 7; ++t) {
      const int m0 = t * 16;
      i32x4 a0v, a1v;
#pragma unroll
      for (int r = 0; r < 4; ++r) {
        a0v[r] = (d0[r] == m0) ? (int)0x3F803F80 : 0;
        a1v[r] = (d1[r] == m0) ? (int)0x3F803F80 : 0;
      }
      const bf16x8 a0 = __builtin_bit_cast(bf16x8, a0v);
      const bf16x8 a1 = __builtin_bit_cast(bf16x8, a1v);
      acc[0][t] = __builtin_amdgcn_mfma_f32_16x16x32_bf16(a0, b00, acc[0][t], 0, 0, 0);
      acc[0][t] = __builtin_amdgcn_mfma_f32_16x16x32_bf16(a1, b10, acc[0][t], 0, 0, 0);
      acc[1][t] = __builtin_amdgcn_mfma_f32_16x16x32_bf16(a0, b01, acc[1][t], 0, 0, 0);
      acc[1][t] = __builtin_amdgcn_mfma_f32_16x16x32_bf16(a1, b11, acc[1][t], 0, 0, 0);
    }
  }
  // ---- block reduce over 4 waves; wave 0 writes chtile 0, wave 1 chtile 1.
  float* pbas = psum + ((size_t)(pqg * 16 + b) * K_) * 256 + cg * 32;
#pragma unroll
  for (int t = 0; t < 7; ++t) {
    s_red[0][wv * 64 + ln] = acc[0][t];
    s_red[1][wv * 64 + ln] = acc[1][t];
    __syncthreads();
    if (wv < 2) {
      const f32x4 a0 = s_red[wv][ln], a1 = s_red[wv][64 + ln];
      const f32x4 a2 = s_red[wv][128 + ln], a3 = s_red[wv][192 + ln];
#pragma unroll
      for (int r = 0; r < 4; ++r) {
        const int row = t * 16 + lg * 4 + r;
        if (row < K_)
          pbas[(size_t)row * 256 + wv * 16 + lc] =
              a0[r] + a1[r] + a2[r] + a3[r];
      }
    }
    __syncthreads();
  }
}

// ---------------------------------------------------------------------------
// K2: normalized prototype slots scaled by 1/sqrt(T) (reads the 8 psum slabs
// directly -- k_reduce folded in), emitted as exact bf16 hi/lo planes; valid
// mask, per-class cnt, column weight, cnt_exist. grid K_ blocks, 256 thr.
// ---------------------------------------------------------------------------
__global__ __launch_bounds__(256) void k_protos(
    const float* __restrict__ psum, const unsigned* __restrict__ counts,
    const float* __restrict__ prototypes, unsigned short* __restrict__ PmH,
    unsigned short* __restrict__ PmL, int* __restrict__ valid,
    float* __restrict__ wcol, float* __restrict__ cntk,
    float* __restrict__ scal) {
  const int k = blockIdx.x;
  const int c = threadIdx.x;  // 0..255 = channel
  __shared__ float red[4];
  __shared__ int s_valid[S_];
  for (int s = 0; s < S_; ++s) {
    float val;
    int pres;
    if (s < B_) {
      const unsigned cb = counts[s * K_ + k];
      float v = 0.f;
#pragma unroll
      for (int pq = 0; pq < NPQ_; ++pq)
        v += psum[((size_t)(pq * 16 + s) * K_ + k) * 256 + c];
      val = v / fmaxf((float)cb, 1.f);
      pres = (cb > 0u) && (k >= 1);
    } else {
      val = prototypes[k * C_ + c];
      pres = (k >= 1);
    }
    float ss = val * val;
#pragma unroll
    for (int o = 32; o > 0; o >>= 1) ss += __shfl_down(ss, o);
    if ((c & 63) == 0) red[c >> 6] = ss;
    __syncthreads();
    const float tot = red[0] + red[1] + red[2] + red[3];
    const float nrm = fmaxf(sqrtf(tot), 1e-12f);
    const float pv = pres ? (val / nrm) * INV_SQRT_T : 0.f;
    const unsigned u = __float_as_uint(pv);
    const float lo = pv - __uint_as_float(u & 0xFFFF0000u);
    const size_t idx = ((size_t)k * S_ + s) * C_ + c;
    PmH[idx] = (unsigned short)(u >> 16);
    PmL[idx] = (unsigned short)(__float_as_uint(lo) >> 16);
    if (c == 0) s_valid[s] = pres;
    __syncthreads();
  }
  if (c == 0) {
    int cnt = 0;
    for (int s = 0; s < S_; ++s) cnt += s_valid[s];
    const float cf = (float)cnt;
    cntk[k] = cf;
    const float wv = 1.f / fmaxf(cf, 1.f);
    for (int s = 0; s < S_; ++s) {
      valid[k * S_ + s] = s_valid[s];
      wcol[k * S_ + s] = s_valid[s] ? wv : 0.f;
    }
    if (cnt > 1 && k >= 1) atomAddGlb(&scal[1], 1.f);
  }
}

// ---------------------------------------------------------------------------
// K3: Gram G = Pm*Pm^T via bf16 MFMA with exact hi/lo split:
// G ~= H*H^T + H*L^T + L*H^T   (lo*lo ~ 2^-16 relative, dropped).
// 64x64 tile per wave, 4 waves/block, grid 196 blocks = 784 tiles.
// ---------------------------------------------------------------------------
__global__ __launch_bounds__(256) void k_gram(
    const unsigned short* __restrict__ PmH,
    const unsigned short* __restrict__ PmL, float* __restrict__ G) {
  const int tid = threadIdx.x;
  const int wv = tid >> 6, ln = tid & 63;
  const int gid = blockIdx.x * 4 + wv;       // 0..783
  const int ri = gid / 28, cj = gid % 28;    // 64x64 tile coords
  const int lg = ln >> 4, lc = ln & 15;

  f32x4 acc[4][4];
#pragma unroll
  for (int m = 0; m < 4; ++m)
#pragma unroll
    for (int n = 0; n < 4; ++n) acc[m][n] = (f32x4)0.f;

#pragma unroll
  for (int ks = 0; ks < 8; ++ks) {
    const int kb = ks * 32 + lg * 8;
    bf16x8 aH[4], aL[4], bH[4], bL[4];
#pragma unroll
    for (int m = 0; m < 4; ++m) {
      const size_t ra = (size_t)(ri * 64 + m * 16 + lc) * C_ + kb;
      aH[m] = __builtin_bit_cast(bf16x8, *(const i32x4*)&PmH[ra]);
      aL[m] = __builtin_bit_cast(bf16x8, *(const i32x4*)&PmL[ra]);
      const size_t rb = (size_t)(cj * 64 + m * 16 + lc) * C_ + kb;
      bH[m] = __builtin_bit_cast(bf16x8, *(const i32x4*)&PmH[rb]);
      bL[m] = __builtin_bit_cast(bf16x8, *(const i32x4*)&PmL[rb]);
    }
#pragma unroll
    for (int m = 0; m < 4; ++m)
#pragma unroll
      for (int n = 0; n < 4; ++n) {
        acc[m][n] = __builtin_amdgcn_mfma_f32_16x16x32_bf16(aH[m], bH[n], acc[m][n], 0, 0, 0);
        acc[m][n] = __builtin_amdgcn_mfma_f32_16x16x32_bf16(aH[m], bL[n], acc[m][n], 0, 0, 0);
        acc[m][n] = __builtin_amdgcn_mfma_f32_16x16x32_bf16(aL[m], bH[n], acc[m][n], 0, 0, 0);
      }
  }
  // D: row = m*16 + lg*4 + r, col = n*16 + lc
#pragma unroll
  for (int m = 0; m < 4; ++m)
#pragma unroll
    for (int r = 0; r < 4; ++r) {
      float* gr = &G[(size_t)(ri * 64 + m * 16 + lg * 4 + r) * GN_ + cj * 64 + lc];
#pragma unroll
      for (int n = 0; n < 4; ++n) gr[n * 16] = acc[m][n][r];
    }
}

// ---------------------------------------------------------------------------
// K4: per-anchor loss. grid (16 slots, 101 classes), block 256.
// ---------------------------------------------------------------------------
__global__ __launch_bounds__(256) void k_loss(
    const float* __restrict__ G, const int* __restrict__ valid,
    const float* __restrict__ wcol, const float* __restrict__ cntk,
    float* __restrict__ scal) {
  const int s = blockIdx.x;  // 0..15 (batch slots only = anchors)
  const int k = blockIdx.y;  // 0..100
  const int a = k * S_ + s;
  if (!valid[a]) return;  // uniform over block
  const int tid = threadIdx.x;
  const float* row = G + (size_t)a * GN_;
  float dpart = 0.f;
  for (int j = tid; j < GN_; j += 256) dpart += wcol[j] * __expf(row[j]);
  __shared__ float red[4];
#pragma unroll
  for (int o = 32; o > 0; o >>= 1) dpart += __shfl_down(dpart, o);
  if ((tid & 63) == 0) red[tid >> 6] = dpart;
  __syncthreads();
  if (tid == 0) {
    const float den = red[0] + red[1] + red[2] + red[3];
    float pos = 0.f;
    for (int n = 0; n < S_; ++n)
      if (valid[k * S_ + n]) pos += row[k * S_ + n];
    pos -= row[a];  // remove self term (diag)
    const float np = cntk[k] - 1.f;
    const float npc = fmaxf(np, 1.f);
    const float pa = -(pos - np * logf(den)) / (npc * npc);
    atomAddGlb(&scal[0], pa);
  }
}

__global__ void k_final(const float* __restrict__ scal, float* __restrict__ out) {
  out[0] = 0.1f * scal[0] / scal[1];
}

// ---------------------------------------------------------------------------
extern "C" void kernel_launch(void* const* d_in, const int* in_sizes, int n_in,
                              void* d_out, int out_size, void* d_ws, size_t ws_size,
                              hipStream_t stream) {
  const int* labels = (const int*)d_in[0];
  const float* feats = (const float*)d_in[1];
  const float* protos = (const float*)d_in[2];
  float* out = (float*)d_out;

  char* wsb = (char*)d_ws;
  size_t o = 0;
  auto nxt = [&](size_t bytes) {
    size_t r = o;
    o = (o + bytes + 255) & ~(size_t)255;
    return r;
  };
  // Small region (memset each call):
  const size_t off_cnts = nxt((size_t)B_ * K_ * 4);
  const size_t off_PH   = nxt((size_t)GN_ * C_ * 2);
  const size_t off_PL   = nxt((size_t)GN_ * C_ * 2);
  const size_t off_val  = nxt((size_t)GN_ * 4);
  const size_t off_w    = nxt((size_t)GN_ * 4);
  const size_t off_cntk = nxt((size_t)K_ * 4);
  const size_t off_scal = nxt(8);
  const size_t small_end = o;
  // Big region: psum partials and G share storage (disjoint lifetimes).
  const size_t psum_bytes = (size_t)NPQ_ * 16 * K_ * 256 * 4;  // 13.2 MB
  const size_t g_bytes = (size_t)GN_ * GN_ * 4;                // 12.8 MB
  const size_t off_big = nxt(psum_bytes > g_bytes ? psum_bytes : g_bytes);

  unsigned* w_cnts = (unsigned*)(wsb + off_cnts);
  unsigned short* w_PH = (unsigned short*)(wsb + off_PH);
  unsigned short* w_PL = (unsigned short*)(wsb + off_PL);
  int* w_valid     = (int*)(wsb + off_val);
  float* w_w       = (float*)(wsb + off_w);
  float* w_cntk    = (float*)(wsb + off_cntk);
  float* w_scal    = (float*)(wsb + off_scal);
  float* w_psum    = (float*)(wsb + off_big);
  float* w_G       = (float*)(wsb + off_big);

  // Zero the small region (PmH/PmL pad rows feed k_gram; scalars accumulate).
  hipMemsetAsync(d_ws, 0, small_end, stream);

  k_segsum<<<1040, 256, 0, stream>>>(labels, feats, w_psum, w_cnts);
  k_protos<<<K_, 256, 0, stream>>>(w_psum, w_cnts, protos, w_PH, w_PL, w_valid,
                                   w_w, w_cntk, w_scal);
  k_gram<<<196, 256, 0, stream>>>(w_PH, w_PL, w_G);
  k_loss<<<dim3(B_, K_), 256, 0, stream>>>(w_G, w_valid, w_w, w_cntk, w_scal);
  k_final<<<1, 1, 0, stream>>>(w_scal, out);
}